// Round 8
// baseline (433.826 us; speedup 1.0000x reference)
//
#include <hip/hip_runtime.h>

// RISnetPIv2: B=128, U=16, A=1024, FEAT=4, INFO=8.
// e_u/e_a uniform averaging -> 32-ch feature factors into ll[B,U,A,8] (bf16),
// lg[B,U,8], gl[B,A,8], gg[B,8] (fp32).
// Round-8: r7 (432us, first win: pk_fma cut VALU 91K->63K cyc/SIMD) + tied
// asm constraints. r7's pk_fma used "=v" with untied accumulator -> allocator
// may emit v_mov_b64 around each of 144 pk_fma/u. "+v" ties D==C (in-place
// accumulate), zero movs. Also: base loaded via 8 float4 (was 16 v2f loads),
// bias likewise. Structure/numerics identical to r7 (passed, absmax 0.00195).

#define NB 128
#define NU 16
#define NA 1024

typedef float v2f __attribute__((ext_vector_type(2)));

static constexpr float PI_F = 3.14159265358979323846f;

// ---- forced VOP3P packed fp32, tied accumulator (no operand copies) ----
__device__ __forceinline__ void pk_fma_acc(v2f& acc, v2f a, v2f b) {
    asm("v_pk_fma_f32 %0, %1, %2, %0" : "+v"(acc) : "v"(a), "v"(b));
}
__device__ __forceinline__ void pk_add_acc(v2f& acc, v2f a) {
    asm("v_pk_add_f32 %0, %1, %0" : "+v"(acc) : "v"(a));
}
// no v_pk_max_f32 on gfx950 -> scalar halves (v_max_f32 x2)
__device__ __forceinline__ v2f relu2(v2f a) {
    return v2f{__builtin_fmaxf(a.x, 0.f), __builtin_fmaxf(a.y, 0.f)};
}

__device__ __forceinline__ void unpack8(uint4 v, float x[8]) {
    x[0] = __uint_as_float(v.x << 16); x[1] = __uint_as_float(v.x & 0xffff0000u);
    x[2] = __uint_as_float(v.y << 16); x[3] = __uint_as_float(v.y & 0xffff0000u);
    x[4] = __uint_as_float(v.z << 16); x[5] = __uint_as_float(v.z & 0xffff0000u);
    x[6] = __uint_as_float(v.w << 16); x[7] = __uint_as_float(v.w & 0xffff0000u);
}
__device__ __forceinline__ void unpack8v(uint4 v, v2f x2[4]) {
    x2[0] = v2f{__uint_as_float(v.x << 16), __uint_as_float(v.x & 0xffff0000u)};
    x2[1] = v2f{__uint_as_float(v.y << 16), __uint_as_float(v.y & 0xffff0000u)};
    x2[2] = v2f{__uint_as_float(v.z << 16), __uint_as_float(v.z & 0xffff0000u)};
    x2[3] = v2f{__uint_as_float(v.w << 16), __uint_as_float(v.w & 0xffff0000u)};
}
__device__ __forceinline__ unsigned int cvtpk(float a, float b) {
    unsigned int r;
    asm("v_cvt_pk_bf16_f32 %0, %1, %2" : "=v"(r) : "v"(a), "v"(b));
    return r;  // lo = bf16(a), hi = bf16(b), RNE
}
__device__ __forceinline__ void store8v(unsigned short* p, const v2f y2[4]) {
    uint4 v;
    v.x = cvtpk(y2[0].x, y2[0].y); v.y = cvtpk(y2[1].x, y2[1].y);
    v.z = cvtpk(y2[2].x, y2[2].y); v.w = cvtpk(y2[3].x, y2[3].y);
    *reinterpret_cast<uint4*>(p) = v;
}
// load 32 floats (8 float4) straight into 16 v2f accumulators
__device__ __forceinline__ void load32_as_v2f(const float* p, v2f y2[16]) {
    const float4* p4 = reinterpret_cast<const float4*>(p);
#pragma unroll
    for (int i = 0; i < 8; ++i) {
        float4 t = p4[i];
        y2[2 * i]     = v2f{t.x, t.y};
        y2[2 * i + 1] = v2f{t.z, t.w};
    }
}

// 3-level channel-merging butterfly: input v2 pairs y[0..3] (8 channels);
// output: lane l holds sum of channel (l&7) over its 8-lane group.
// Follow with LDS atomic add from all 64 lanes for full block sum.
__device__ __forceinline__ float merge3v(const v2f* y, int lane) {
    float w[4];
    const bool s0 = (lane & 1) != 0;
#pragma unroll
    for (int k = 0; k < 4; ++k) {
        float lo = s0 ? y[k].y : y[k].x;
        float hi = s0 ? y[k].x : y[k].y;
        w[k] = lo + __shfl_xor(hi, 1, 64);
    }
    const bool s1 = (lane & 2) != 0;
#pragma unroll
    for (int k = 0; k < 2; ++k) {
        float lo = s1 ? w[2 * k + 1] : w[2 * k];
        float hi = s1 ? w[2 * k] : w[2 * k + 1];
        w[k] = lo + __shfl_xor(hi, 2, 64);
    }
    const bool s2 = (lane & 4) != 0;
    float lo = s2 ? w[1] : w[0];
    float hi = s2 ? w[0] : w[1];
    return lo + __shfl_xor(hi, 4, 64);
}

// ---------------- Layer 1: input channel [B,4,U,A] ----------------
template <int NZ>
__global__ __launch_bounds__(128) void layer_first_t(
    const float* __restrict__ ch, const float* __restrict__ W1,
    const float* __restrict__ b1, unsigned short* __restrict__ ll_out,
    float* __restrict__ lg_out, float* __restrict__ gl_out,
    float* __restrict__ gg_out)
{
    constexpr int UN = NU / NZ;
    const int b = blockIdx.x;
    const int a = blockIdx.y * 128 + threadIdx.x;
    const int uz = blockIdx.z;
    const int lane = threadIdx.x & 63;
    const int tid = threadIdx.x;
    const v2f zero = v2f{0.f, 0.f};

    __shared__ float s_lg[UN][8];
    __shared__ float s_gg[8];
    if (tid < UN * 8) s_lg[tid >> 3][tid & 7] = 0.f;
    if (tid >= 64 && tid < 72) s_gg[tid & 7] = 0.f;
    __syncthreads();

    v2f glacc2[4], ggacc2[4];
#pragma unroll
    for (int i = 0; i < 4; ++i) { glacc2[i] = zero; ggacc2[i] = zero; }

#pragma unroll
    for (int k = 0; k < UN; ++k) {
        const int u = uz * UN + k;
        float x[4];
#pragma unroll
        for (int c = 0; c < 4; ++c)
            x[c] = ch[(((size_t)b * 4 + c) * NU + u) * NA + a];

        v2f y2[16];
        load32_as_v2f(b1, y2);
#pragma unroll
        for (int c = 0; c < 4; ++c) {
            const v2f xx = v2f{x[c], x[c]};
#pragma unroll
            for (int j = 0; j < 4; ++j) {
                const v2f* wr = reinterpret_cast<const v2f*>(W1 + (j * 4 + c) * 8);
#pragma unroll
                for (int oi = 0; oi < 4; ++oi)
                    pk_fma_acc(y2[j * 4 + oi], xx, wr[oi]);
            }
        }
#pragma unroll
        for (int o = 0; o < 16; ++o) y2[o] = relu2(y2[o]);

        const size_t xoff = (((size_t)(b * NU + u)) * NA + a) * 8;
        store8v(ll_out + xoff, y2);                     // ch 0-7

#pragma unroll
        for (int i = 0; i < 4; ++i) pk_add_acc(glacc2[i], y2[8 + i]);
#pragma unroll
        for (int i = 0; i < 4; ++i) pk_add_acc(ggacc2[i], y2[12 + i]);

        float lr = merge3v(y2 + 4, lane);               // ch 8-15 -> lg
        atomicAdd(&s_lg[k][lane & 7], lr);
    }
    {   // gl partial for this u-slice (scaled 1/U; partials sum to mean)
        const float invU = 1.f / 16.f;
        float4* gp = reinterpret_cast<float4*>(
            gl_out + (((size_t)uz * NB + b) * NA + a) * 8);
        gp[0] = make_float4(glacc2[0].x*invU, glacc2[0].y*invU, glacc2[1].x*invU, glacc2[1].y*invU);
        gp[1] = make_float4(glacc2[2].x*invU, glacc2[2].y*invU, glacc2[3].x*invU, glacc2[3].y*invU);
    }
    float gr = merge3v(ggacc2, lane);
    atomicAdd(&s_gg[lane & 7], gr);
    __syncthreads();
    if (tid < UN * 8)
        atomicAdd(lg_out + ((size_t)b * NU + uz * UN + (tid >> 3)) * 8 + (tid & 7),
                  s_lg[tid >> 3][tid & 7]);
    if (tid >= 64 && tid < 72)
        atomicAdd(gg_out + b * 8 + (tid & 7), s_gg[tid & 7]);
}

// -------- prep: base[b,u,32] = bias + lg·W_lg + gg·W_gg (optional input skip) ----
__global__ __launch_bounds__(256) void prep_base_k(
    const float* __restrict__ lg_sum, const float* __restrict__ lg_skip,
    const float* __restrict__ gg_sum, const float* __restrict__ gg_skip,
    const float* __restrict__ Wl, const float* __restrict__ bl,
    float* __restrict__ base)
{
    const int t = blockIdx.x * 256 + threadIdx.x;  // b*16+u
    if (t >= NB * NU) return;
    const int b = t >> 4;
    const float invA = 1.f / 1024.f, invUA = 1.f / 16384.f;
    float lg[8], gg[8];
#pragma unroll
    for (int c = 0; c < 8; ++c) {
        float v = lg_sum[t * 8 + c] * invA;
        if (lg_skip) v = (v + lg_skip[t * 8 + c] * invA) * 0.5f;
        lg[c] = v;
    }
#pragma unroll
    for (int c = 0; c < 8; ++c) {
        float v = gg_sum[b * 8 + c] * invUA;
        if (gg_skip) v = (v + gg_skip[b * 8 + c] * invUA) * 0.5f;
        gg[c] = v;
    }
    float y[32];
#pragma unroll
    for (int o = 0; o < 32; ++o) y[o] = bl[o];
#pragma unroll
    for (int j = 0; j < 4; ++j)
#pragma unroll
        for (int c = 0; c < 8; ++c) {
            const float* wl = Wl + (j * 32 + 8 + c) * 8;
            const float* wg = Wl + (j * 32 + 24 + c) * 8;
#pragma unroll
            for (int oi = 0; oi < 8; ++oi) {
                y[j * 8 + oi] = fmaf(lg[c], wl[oi], y[j * 8 + oi]);
                y[j * 8 + oi] = fmaf(gg[c], wg[oi], y[j * 8 + oi]);
            }
        }
#pragma unroll
    for (int o = 0; o < 32; ++o) base[t * 32 + o] = y[o];
}

// ---------------- Layers 2..7 main ----------------
// ll_in / ll_out may alias (per-thread read-then-write of same position;
// prefetch of u+1 is this thread's own position, written only at its own
// k+1 iteration -> safe; z-blocks own disjoint u-slices).
template <int NZ>
__global__ __launch_bounds__(128) void layer_main_t(
    const unsigned short* ll_in, const float* __restrict__ gl_in,
    const float* __restrict__ gl_skip, const float* __restrict__ base,
    const float* __restrict__ Wl,
    const unsigned short* __restrict__ ll_skip,          // layer 7: f3 ll
    const float* __restrict__ ch, const float* __restrict__ W1,
    const float* __restrict__ b1,                        // layer 5: recompute f1 ll
    unsigned short* ll_out, float* __restrict__ lg_out,
    float* __restrict__ gl_out, float* __restrict__ gg_out)
{
    constexpr int UN = NU / NZ;
    const int b = blockIdx.x;
    const int a = blockIdx.y * 128 + threadIdx.x;
    const int uz = blockIdx.z;
    const int lane = threadIdx.x & 63;
    const int tid = threadIdx.x;
    const v2f zero = v2f{0.f, 0.f};

    __shared__ float s_lg[UN][8];
    __shared__ float s_gg[8];
    if (tid < UN * 8) s_lg[tid >> 3][tid & 7] = 0.f;
    if (tid >= 64 && tid < 72) s_gg[tid & 7] = 0.f;
    __syncthreads();

    // gl gather (+ optional skip average)
    float g[8];
    {
        float si[8];
#pragma unroll
        for (int i = 0; i < 8; ++i) si[i] = 0.f;
#pragma unroll
        for (int z = 0; z < NZ; ++z) {
            const float4* gp = reinterpret_cast<const float4*>(
                gl_in + (((size_t)z * NB + b) * NA + a) * 8);
            float4 g0 = gp[0], g1 = gp[1];
            si[0] += g0.x; si[1] += g0.y; si[2] += g0.z; si[3] += g0.w;
            si[4] += g1.x; si[5] += g1.y; si[6] += g1.z; si[7] += g1.w;
        }
        if (gl_skip) {
            float ss[8];
#pragma unroll
            for (int i = 0; i < 8; ++i) ss[i] = 0.f;
#pragma unroll
            for (int z = 0; z < NZ; ++z) {
                const float4* sp = reinterpret_cast<const float4*>(
                    gl_skip + (((size_t)z * NB + b) * NA + a) * 8);
                float4 s0 = sp[0], s1 = sp[1];
                ss[0] += s0.x; ss[1] += s0.y; ss[2] += s0.z; ss[3] += s0.w;
                ss[4] += s1.x; ss[5] += s1.y; ss[6] += s1.z; ss[7] += s1.w;
            }
#pragma unroll
            for (int i = 0; i < 8; ++i) g[i] = (si[i] + ss[i]) * 0.5f;
        } else {
#pragma unroll
            for (int i = 0; i < 8; ++i) g[i] = si[i];
        }
    }
    // cgl = gl contribution to all 32 out-channels (constant over u)
    v2f cgl2[16];
#pragma unroll
    for (int o = 0; o < 16; ++o) cgl2[o] = zero;
#pragma unroll
    for (int c = 0; c < 8; ++c) {
        const v2f xx = v2f{g[c], g[c]};
#pragma unroll
        for (int j = 0; j < 4; ++j) {
            const v2f* wr = reinterpret_cast<const v2f*>(Wl + (j * 32 + 16 + c) * 8);
#pragma unroll
            for (int oi = 0; oi < 4; ++oi)
                pk_fma_acc(cgl2[j * 4 + oi], xx, wr[oi]);
        }
    }

    v2f glacc2[4], ggacc2[4];
#pragma unroll
    for (int i = 0; i < 4; ++i) { glacc2[i] = zero; ggacc2[i] = zero; }

    const unsigned short* llp =
        ll_in + (((size_t)(b * NU + uz * UN)) * NA + a) * 8;
    const size_t ustride = (size_t)NA * 8;
    uint4 xv = *reinterpret_cast<const uint4*>(llp);

#pragma unroll
    for (int k = 0; k < UN; ++k) {
        const int u = uz * UN + k;
        uint4 xnext = xv;
        if (k + 1 < UN)
            xnext = *reinterpret_cast<const uint4*>(llp + (size_t)(k + 1) * ustride);

        // y2 = base[u] (8x float4 loads) ; y2 += cgl (tied pk_add)
        v2f y2[16];
        load32_as_v2f(base + (b * NU + u) * 32, y2);
#pragma unroll
        for (int o = 0; o < 16; ++o) pk_add_acc(y2[o], cgl2[o]);

        float x[8];
        unpack8(xv, x);
#pragma unroll
        for (int c = 0; c < 8; ++c) {
            const v2f xx = v2f{x[c], x[c]};
#pragma unroll
            for (int j = 0; j < 4; ++j) {
                const v2f* wr = reinterpret_cast<const v2f*>(Wl + (j * 32 + c) * 8);
#pragma unroll
                for (int oi = 0; oi < 4; ++oi)
                    pk_fma_acc(y2[j * 4 + oi], xx, wr[oi]);
            }
        }
#pragma unroll
        for (int o = 0; o < 16; ++o) y2[o] = relu2(y2[o]);

        const size_t xoff = (((size_t)(b * NU + u)) * NA + a) * 8;
        v2f out2[4];
#pragma unroll
        for (int i = 0; i < 4; ++i) out2[i] = y2[i];
        if (ll_skip) {                       // layer 7: average with stored f3 ll
            v2f s2[4];
            unpack8v(*reinterpret_cast<const uint4*>(ll_skip + xoff), s2);
#pragma unroll
            for (int i = 0; i < 4; ++i) out2[i] = (out2[i] + s2[i]) * 0.5f;
        } else if (ch) {                     // layer 5: recompute f1 ll from input
            float xc[4];
#pragma unroll
            for (int c = 0; c < 4; ++c)
                xc[c] = ch[(((size_t)b * 4 + c) * NU + u) * NA + a];
            v2f s2[4];
            const v2f* b12 = reinterpret_cast<const v2f*>(b1);
#pragma unroll
            for (int i = 0; i < 4; ++i) s2[i] = b12[i];
#pragma unroll
            for (int c = 0; c < 4; ++c) {
                const v2f* w2 = reinterpret_cast<const v2f*>(W1 + c * 8);
                const v2f xx = v2f{xc[c], xc[c]};
#pragma unroll
                for (int i = 0; i < 4; ++i) pk_fma_acc(s2[i], xx, w2[i]);
            }
#pragma unroll
            for (int i = 0; i < 4; ++i)
                out2[i] = (out2[i] + relu2(s2[i])) * 0.5f;
        }
        store8v(ll_out + xoff, out2);

#pragma unroll
        for (int i = 0; i < 4; ++i) pk_add_acc(glacc2[i], y2[8 + i]);
#pragma unroll
        for (int i = 0; i < 4; ++i) pk_add_acc(ggacc2[i], y2[12 + i]);

        float lr = merge3v(y2 + 4, lane);    // ch 8-15 -> lg
        atomicAdd(&s_lg[k][lane & 7], lr);

        xv = xnext;
    }
    {
        const float invU = 1.f / 16.f;
        float4* gp = reinterpret_cast<float4*>(
            gl_out + (((size_t)uz * NB + b) * NA + a) * 8);
        gp[0] = make_float4(glacc2[0].x*invU, glacc2[0].y*invU, glacc2[1].x*invU, glacc2[1].y*invU);
        gp[1] = make_float4(glacc2[2].x*invU, glacc2[2].y*invU, glacc2[3].x*invU, glacc2[3].y*invU);
    }
    float gr = merge3v(ggacc2, lane);
    atomicAdd(&s_gg[lane & 7], gr);
    __syncthreads();
    if (tid < UN * 8)
        atomicAdd(lg_out + ((size_t)b * NU + uz * UN + (tid >> 3)) * 8 + (tid & 7),
                  s_lg[tid >> 3][tid & 7]);
    if (tid >= 64 && tid < 72)
        atomicAdd(gg_out + b * 8 + (tid & 7), s_gg[tid & 7]);
}

// ---------------- Layer 8: out[b,a] = pi * (mean_u f·W8 + b8) ----------------
// z-split partials accumulate via atomicAdd into a zeroed output.
template <int NZ>
__global__ __launch_bounds__(128) void layer_out_t(
    const unsigned short* __restrict__ ll,   // f7' ll (skip already applied)
    const float* __restrict__ lg7, const float* __restrict__ lg3,  // raw sums
    const float* __restrict__ gl7, const float* __restrict__ gl3,  // partial means
    const float* __restrict__ gg7, const float* __restrict__ gg3,  // raw sums
    const float* __restrict__ W8, const float* __restrict__ b8,
    float* __restrict__ out)
{
    constexpr int UN = NU / NZ;
    const int b = blockIdx.x;
    const int a = blockIdx.y * 128 + threadIdx.x;
    const int uz = blockIdx.z;
    const float invA = 1.f / 1024.f, invUA = 1.f / 16384.f, invU = 1.f / 16.f;

    float acc = 0.f;
#pragma unroll
    for (int k = 0; k < UN; ++k) {
        const int u = uz * UN + k;
        float x[8];
        unpack8(*reinterpret_cast<const uint4*>(
            ll + (((size_t)(b * NU + u)) * NA + a) * 8), x);
#pragma unroll
        for (int c = 0; c < 8; ++c) acc += x[c] * W8[c];
    }
    acc *= invU;

    if (uz == 0) {
        float sb = b8[0];
#pragma unroll
        for (int c = 0; c < 8; ++c) {
            float s7 = 0.f, s3 = 0.f;
#pragma unroll
            for (int u = 0; u < NU; ++u) {
                s7 += lg7[(b * NU + u) * 8 + c];
                s3 += lg3[(b * NU + u) * 8 + c];
            }
            sb += ((s7 * invA + s3 * invA) * 0.5f * invU) * W8[8 + c];
        }
#pragma unroll
        for (int c = 0; c < 8; ++c)
            sb += ((gg7[b * 8 + c] + gg3[b * 8 + c]) * invUA * 0.5f) * W8[24 + c];

        float s7[8], s3[8];
#pragma unroll
        for (int i = 0; i < 8; ++i) { s7[i] = 0.f; s3[i] = 0.f; }
#pragma unroll
        for (int z = 0; z < NZ; ++z) {
            const float4* g7 = reinterpret_cast<const float4*>(
                gl7 + (((size_t)z * NB + b) * NA + a) * 8);
            const float4* g3 = reinterpret_cast<const float4*>(
                gl3 + (((size_t)z * NB + b) * NA + a) * 8);
            float4 a0 = g7[0], a1 = g7[1], b0 = g3[0], b1v = g3[1];
            s7[0] += a0.x; s7[1] += a0.y; s7[2] += a0.z; s7[3] += a0.w;
            s7[4] += a1.x; s7[5] += a1.y; s7[6] += a1.z; s7[7] += a1.w;
            s3[0] += b0.x; s3[1] += b0.y; s3[2] += b0.z; s3[3] += b0.w;
            s3[4] += b1v.x; s3[5] += b1v.y; s3[6] += b1v.z; s3[7] += b1v.w;
        }
#pragma unroll
        for (int i = 0; i < 8; ++i)
            acc += 0.5f * (s7[i] + s3[i]) * W8[16 + i];
        acc += sb;
    }
    atomicAdd(out + (size_t)b * NA + a, acc * PI_F);
}

// ---------------- host ----------------
static constexpr size_t LLsz = (size_t)NB * NU * NA * 8;  // elems
static constexpr size_t GLsz = (size_t)NB * NA * 8;
static constexpr size_t LGsz = (size_t)NB * NU * 8;
static constexpr size_t GGsz = (size_t)NB * 8;

template <int NZ>
static void run_pipeline(const float* channel, const float* W1, const float* b1,
                         const float* Wm, const float* bm, const float* W8,
                         const float* b8, float* out, int out_bytes,
                         void* d_ws, hipStream_t stream)
{
    unsigned short* cur = (unsigned short*)d_ws;        // bf16 ll
    unsigned short* f3s = cur + LLsz;                   // bf16 f3 ll copy
    float* glb = (float*)(f3s + LLsz);                  // 4 bufs x NZ*GL fp32
    float* g0 = glb;
    float* g1 = glb + (size_t)NZ * GLsz;
    float* g2 = glb + (size_t)2 * NZ * GLsz;
    float* g3 = glb + (size_t)3 * NZ * GLsz;
    float* lgb = glb + (size_t)4 * NZ * GLsz;           // 7 x LG
    float* ggb = lgb + 7 * LGsz;                        // 7 x GG
    float* base = ggb + 7 * GGsz;                       // 2048 x 32

    hipMemsetAsync(lgb, 0, (7 * LGsz + 7 * GGsz) * sizeof(float), stream);
    hipMemsetAsync(out, 0, out_bytes, stream);

    dim3 grid(NB, NA / 128, NZ), blk(128);

    // L1: f1 -> cur, g0, lgb0, ggb0
    layer_first_t<NZ><<<grid, blk, 0, stream>>>(channel, W1, b1, cur, lgb, g0, ggb);

    // L2: cur -> cur (in-place), g0 -> g2
    prep_base_k<<<8, 256, 0, stream>>>(lgb, nullptr, ggb, nullptr, Wm, bm, base);
    layer_main_t<NZ><<<grid, blk, 0, stream>>>(cur, g0, nullptr, base, Wm,
        nullptr, nullptr, nullptr, nullptr,
        cur, lgb + 1 * LGsz, g2, ggb + 1 * GGsz);

    // L3: cur -> f3s (pinned f3 copy), g2 -> g1
    prep_base_k<<<8, 256, 0, stream>>>(lgb + 1 * LGsz, nullptr, ggb + 1 * GGsz, nullptr,
                                       Wm + 1024, bm + 32, base);
    layer_main_t<NZ><<<grid, blk, 0, stream>>>(cur, g2, nullptr, base, Wm + 1024,
        nullptr, nullptr, nullptr, nullptr,
        f3s, lgb + 2 * LGsz, g1, ggb + 2 * GGsz);

    // L4: f3s -> cur, g1 -> g3
    prep_base_k<<<8, 256, 0, stream>>>(lgb + 2 * LGsz, nullptr, ggb + 2 * GGsz, nullptr,
                                       Wm + 2048, bm + 64, base);
    layer_main_t<NZ><<<grid, blk, 0, stream>>>(f3s, g1, nullptr, base, Wm + 2048,
        nullptr, nullptr, nullptr, nullptr,
        cur, lgb + 3 * LGsz, g3, ggb + 3 * GGsz);

    // L5: cur -> cur, g3 -> g2; ll-skip = recomputed f1 from channel
    prep_base_k<<<8, 256, 0, stream>>>(lgb + 3 * LGsz, nullptr, ggb + 3 * GGsz, nullptr,
                                       Wm + 3072, bm + 96, base);
    layer_main_t<NZ><<<grid, blk, 0, stream>>>(cur, g3, nullptr, base, Wm + 3072,
        nullptr, channel, W1, b1,
        cur, lgb + 4 * LGsz, g2, ggb + 4 * GGsz);

    // L6: cur -> cur, g2 -> g3; input-side skip with f1 factors (lgb0/ggb0/g0)
    prep_base_k<<<8, 256, 0, stream>>>(lgb + 4 * LGsz, lgb, ggb + 4 * GGsz, ggb,
                                       Wm + 4096, bm + 128, base);
    layer_main_t<NZ><<<grid, blk, 0, stream>>>(cur, g2, g0, base, Wm + 4096,
        nullptr, nullptr, nullptr, nullptr,
        cur, lgb + 5 * LGsz, g3, ggb + 5 * GGsz);

    // L7: cur -> cur, g3 -> g2; ll-skip = f3s
    prep_base_k<<<8, 256, 0, stream>>>(lgb + 5 * LGsz, nullptr, ggb + 5 * GGsz, nullptr,
                                       Wm + 5120, bm + 160, base);
    layer_main_t<NZ><<<grid, blk, 0, stream>>>(cur, g3, nullptr, base, Wm + 5120,
        f3s, nullptr, nullptr, nullptr,
        cur, lgb + 6 * LGsz, g2, ggb + 6 * GGsz);

    // L8
    layer_out_t<NZ><<<grid, blk, 0, stream>>>(cur, lgb + 6 * LGsz, lgb + 2 * LGsz,
                                              g2, g1, ggb + 6 * GGsz, ggb + 2 * GGsz,
                                              W8, b8, out);
}

static size_t ws_req(int nz) {
    return LLsz * 2 * sizeof(unsigned short)            // cur + f3s (bf16)
         + (size_t)4 * nz * GLsz * sizeof(float)
         + (7 * LGsz + 7 * GGsz + 2048 * 32) * sizeof(float);
}

extern "C" void kernel_launch(void* const* d_in, const int* in_sizes, int n_in,
                              void* d_out, int out_size, void* d_ws, size_t ws_size,
                              hipStream_t stream) {
    const float* channel = (const float*)d_in[0];
    const float* W1 = (const float*)d_in[1];
    const float* b1 = (const float*)d_in[2];
    const float* Wm = (const float*)d_in[3];
    const float* bm = (const float*)d_in[4];
    const float* W8 = (const float*)d_in[5];
    const float* b8 = (const float*)d_in[6];
    float* out = (float*)d_out;

    if (ws_size >= ws_req(4)) {
        run_pipeline<4>(channel, W1, b1, Wm, bm, W8, b8, out, out_size, d_ws, stream);
    } else if (ws_size >= ws_req(2)) {
        run_pipeline<2>(channel, W1, b1, Wm, bm, W8, b8, out, out_size, d_ws, stream);
    } else {
        run_pipeline<1>(channel, W1, b1, Wm, bm, W8, b8, out, out_size, d_ws, stream);
    }
}

// Round 9
// 416.525 us; speedup vs baseline: 1.0415x; 1.0415x over previous
//
#include <hip/hip_runtime.h>

// RISnetPIv2: B=128, U=16, A=1024, FEAT=4, INFO=8.
// Round-9: MFMA rewrite of layer_main. Diagnosis: the 128 v2f weights of the
// 8->32 conv cannot be register-resident (256 VGPR) -> ~128 weight loads
// re-issued EVERY u-iteration = the 3x instruction bloat + latency. One
// v_mfma_f32_32x32x16_bf16 holds all weights in a 4-VGPR B-fragment.
// K=16 split: A k0-7 = x, k8-15 = x; B k0-7 = bf16(W), k8-15 = bf16(W-bf16(W))
// -> x*W to ~2^-17 weight precision in ONE mfma (no absmax risk). 2 mfma/u.
// D layout (HW-verified): col=lane&31 (channel), row=(reg&3)+8*(reg>>2)+
// 4*(lane>>5) (antenna). lg = rowsum+shfl; gl/gg = vector accumulate;
// ch0-7 transposed to antenna-major via tiny per-wave LDS bounce; skip
// paths (f3 avg, L5 recompute) run post-transpose, numerics unchanged.
// gl buffers now channel-plane layout [uz][b][8][A] (L1/L8 updated).

#define NB 128
#define NU 16
#define NA 1024

typedef float v2f __attribute__((ext_vector_type(2)));
typedef __attribute__((ext_vector_type(8))) short bf16x8;
typedef __attribute__((ext_vector_type(16))) float f32x16;

static constexpr float PI_F = 3.14159265358979323846f;

__device__ __forceinline__ void pk_fma_acc(v2f& acc, v2f a, v2f b) {
    asm("v_pk_fma_f32 %0, %1, %2, %0" : "+v"(acc) : "v"(a), "v"(b));
}
__device__ __forceinline__ unsigned int cvtpk(float a, float b) {
    unsigned int r;
    asm("v_cvt_pk_bf16_f32 %0, %1, %2" : "=v"(r) : "v"(a), "v"(b));
    return r;  // lo = bf16(a), hi = bf16(b), RNE
}
__device__ __forceinline__ void unpack8(uint4 v, float x[8]) {
    x[0] = __uint_as_float(v.x << 16); x[1] = __uint_as_float(v.x & 0xffff0000u);
    x[2] = __uint_as_float(v.y << 16); x[3] = __uint_as_float(v.y & 0xffff0000u);
    x[4] = __uint_as_float(v.z << 16); x[5] = __uint_as_float(v.z & 0xffff0000u);
    x[6] = __uint_as_float(v.w << 16); x[7] = __uint_as_float(v.w & 0xffff0000u);
}
__device__ __forceinline__ void store8f(unsigned short* p, const float y[8]) {
    uint4 v;
    v.x = cvtpk(y[0], y[1]); v.y = cvtpk(y[2], y[3]);
    v.z = cvtpk(y[4], y[5]); v.w = cvtpk(y[6], y[7]);
    *reinterpret_cast<uint4*>(p) = v;
}
__device__ __forceinline__ float treesum16(f32x16 v) {
    float a0 = v[0] + v[1], a1 = v[2] + v[3], a2 = v[4] + v[5], a3 = v[6] + v[7];
    float a4 = v[8] + v[9], a5 = v[10] + v[11], a6 = v[12] + v[13], a7 = v[14] + v[15];
    float b0 = a0 + a1, b1 = a2 + a3, b2 = a4 + a5, b3 = a6 + a7;
    return (b0 + b1) + (b2 + b3);
}

// 3-level channel-merging butterfly (layer_first only, proven r7)
__device__ __forceinline__ float merge3v(const v2f* y, int lane) {
    float w[4];
    const bool s0 = (lane & 1) != 0;
#pragma unroll
    for (int k = 0; k < 4; ++k) {
        float lo = s0 ? y[k].y : y[k].x;
        float hi = s0 ? y[k].x : y[k].y;
        w[k] = lo + __shfl_xor(hi, 1, 64);
    }
    const bool s1 = (lane & 2) != 0;
#pragma unroll
    for (int k = 0; k < 2; ++k) {
        float lo = s1 ? w[2 * k + 1] : w[2 * k];
        float hi = s1 ? w[2 * k] : w[2 * k + 1];
        w[k] = lo + __shfl_xor(hi, 2, 64);
    }
    const bool s2 = (lane & 4) != 0;
    float lo = s2 ? w[1] : w[0];
    float hi = s2 ? w[0] : w[1];
    return lo + __shfl_xor(hi, 4, 64);
}

// ---------------- Layer 1 (VALU, K=4 fp32 input; gl -> plane layout) -------
template <int NZ>
__global__ __launch_bounds__(128) void layer_first_t(
    const float* __restrict__ ch, const float* __restrict__ W1,
    const float* __restrict__ b1, unsigned short* __restrict__ ll_out,
    float* __restrict__ lg_out, float* __restrict__ gl_out,
    float* __restrict__ gg_out)
{
    constexpr int UN = NU / NZ;
    const int b = blockIdx.x;
    const int a = blockIdx.y * 128 + threadIdx.x;
    const int uz = blockIdx.z;
    const int lane = threadIdx.x & 63;
    const int tid = threadIdx.x;
    const v2f zero = v2f{0.f, 0.f};

    __shared__ float s_lg[UN][8];
    __shared__ float s_gg[8];
    if (tid < UN * 8) s_lg[tid >> 3][tid & 7] = 0.f;
    if (tid >= 64 && tid < 72) s_gg[tid & 7] = 0.f;
    __syncthreads();

    v2f glacc2[4], ggacc2[4];
#pragma unroll
    for (int i = 0; i < 4; ++i) { glacc2[i] = zero; ggacc2[i] = zero; }

#pragma unroll
    for (int k = 0; k < UN; ++k) {
        const int u = uz * UN + k;
        float x[4];
#pragma unroll
        for (int c = 0; c < 4; ++c)
            x[c] = ch[(((size_t)b * 4 + c) * NU + u) * NA + a];

        v2f y2[16];
        const v2f* b2 = reinterpret_cast<const v2f*>(b1);
#pragma unroll
        for (int o = 0; o < 16; ++o) y2[o] = b2[o];
#pragma unroll
        for (int c = 0; c < 4; ++c) {
            const v2f xx = v2f{x[c], x[c]};
#pragma unroll
            for (int j = 0; j < 4; ++j) {
                const v2f* wr = reinterpret_cast<const v2f*>(W1 + (j * 4 + c) * 8);
#pragma unroll
                for (int oi = 0; oi < 4; ++oi)
                    pk_fma_acc(y2[j * 4 + oi], xx, wr[oi]);
            }
        }
#pragma unroll
        for (int o = 0; o < 16; ++o)
            y2[o] = v2f{__builtin_fmaxf(y2[o].x, 0.f), __builtin_fmaxf(y2[o].y, 0.f)};

        const size_t xoff = (((size_t)(b * NU + u)) * NA + a) * 8;
        {
            uint4 v;
            v.x = cvtpk(y2[0].x, y2[0].y); v.y = cvtpk(y2[1].x, y2[1].y);
            v.z = cvtpk(y2[2].x, y2[2].y); v.w = cvtpk(y2[3].x, y2[3].y);
            *reinterpret_cast<uint4*>(ll_out + xoff) = v;
        }
#pragma unroll
        for (int i = 0; i < 4; ++i) {
            glacc2[i] += y2[8 + i];
            ggacc2[i] += y2[12 + i];
        }
        float lr = merge3v(y2 + 4, lane);
        atomicAdd(&s_lg[k][lane & 7], lr);
    }
    {   // gl partial, channel-plane layout [uz][b][c][a]
        const float invU = 1.f / 16.f;
        float ga[8];
#pragma unroll
        for (int i = 0; i < 4; ++i) { ga[2*i] = glacc2[i].x; ga[2*i+1] = glacc2[i].y; }
#pragma unroll
        for (int c = 0; c < 8; ++c)
            gl_out[(((size_t)uz * NB + b) * 8 + c) * NA + a] = ga[c] * invU;
    }
    float gga[8];
#pragma unroll
    for (int i = 0; i < 4; ++i) { gga[2*i] = ggacc2[i].x; gga[2*i+1] = ggacc2[i].y; }
    float gr = merge3v(reinterpret_cast<const v2f*>(gga), lane);
    atomicAdd(&s_gg[lane & 7], gr);
    __syncthreads();
    if (tid < UN * 8)
        atomicAdd(lg_out + ((size_t)b * NU + uz * UN + (tid >> 3)) * 8 + (tid & 7),
                  s_lg[tid >> 3][tid & 7]);
    if (tid >= 64 && tid < 72)
        atomicAdd(gg_out + b * 8 + (tid & 7), s_gg[tid & 7]);
}

// -------- prep: base[b,u,32] = bias + lg·W_lg + gg·W_gg (unchanged) --------
__global__ __launch_bounds__(256) void prep_base_k(
    const float* __restrict__ lg_sum, const float* __restrict__ lg_skip,
    const float* __restrict__ gg_sum, const float* __restrict__ gg_skip,
    const float* __restrict__ Wl, const float* __restrict__ bl,
    float* __restrict__ base)
{
    const int t = blockIdx.x * 256 + threadIdx.x;  // b*16+u
    if (t >= NB * NU) return;
    const int b = t >> 4;
    const float invA = 1.f / 1024.f, invUA = 1.f / 16384.f;
    float lg[8], gg[8];
#pragma unroll
    for (int c = 0; c < 8; ++c) {
        float v = lg_sum[t * 8 + c] * invA;
        if (lg_skip) v = (v + lg_skip[t * 8 + c] * invA) * 0.5f;
        lg[c] = v;
    }
#pragma unroll
    for (int c = 0; c < 8; ++c) {
        float v = gg_sum[b * 8 + c] * invUA;
        if (gg_skip) v = (v + gg_skip[b * 8 + c] * invUA) * 0.5f;
        gg[c] = v;
    }
    float y[32];
#pragma unroll
    for (int o = 0; o < 32; ++o) y[o] = bl[o];
#pragma unroll
    for (int j = 0; j < 4; ++j)
#pragma unroll
        for (int c = 0; c < 8; ++c) {
            const float* wl = Wl + (j * 32 + 8 + c) * 8;
            const float* wg = Wl + (j * 32 + 24 + c) * 8;
#pragma unroll
            for (int oi = 0; oi < 8; ++oi) {
                y[j * 8 + oi] = fmaf(lg[c], wl[oi], y[j * 8 + oi]);
                y[j * 8 + oi] = fmaf(gg[c], wg[oi], y[j * 8 + oi]);
            }
        }
#pragma unroll
    for (int o = 0; o < 32; ++o) base[t * 32 + o] = y[o];
}

// ---------------- Layers 2..7: MFMA version ----------------
// In-place safe: each lane reads/writes its OWN (b,u,a) row; cross-lane shfl
// of xv happens before the store in the same iteration (wave lockstep).
template <int NZ>
__global__ __launch_bounds__(128) void layer_main_t(
    const unsigned short* ll_in, const float* __restrict__ gl_in,
    const float* __restrict__ gl_skip, const float* __restrict__ base,
    const float* __restrict__ Wl,
    const unsigned short* __restrict__ ll_skip,          // layer 7: f3 ll
    const float* __restrict__ ch, const float* __restrict__ W1,
    const float* __restrict__ b1,                        // layer 5: recompute f1
    unsigned short* ll_out, float* __restrict__ lg_out,
    float* __restrict__ gl_out, float* __restrict__ gg_out)
{
    constexpr int UN = NU / NZ;
    const int b = blockIdx.x;
    const int tid = threadIdx.x;
    const int wav = tid >> 6;
    const int lane = tid & 63;
    const int o = lane & 31;            // channel id in MFMA D space
    const int h4 = 4 * (lane >> 5);     // row-offset of this half-wave
    const int a = blockIdx.y * 128 + tid;
    const int uz = blockIdx.z;

    __shared__ float s_lg[UN][8];
    __shared__ float s_gg[8];
    __shared__ float ldsw[2][64 * 36];  // per-wave: cglT [64][36]; reused [8][68] tb
    if (tid < UN * 8) s_lg[tid >> 3][tid & 7] = 0.f;
    if (tid >= 64 && tid < 72) s_gg[tid & 7] = 0.f;
    float* myl = ldsw[wav];

    // ---- B fragment: col o; k0-7 = bf16(W), k8-15 = bf16(W - bf16(W)) ----
    bf16x8 Bfrag;
    {
        const int jbr = o >> 3, oi = o & 7;
        uint4 bw;
        unsigned int t4[4];
#pragma unroll
        for (int r = 0; r < 4; ++r) {
            float w0 = Wl[(jbr * 32 + 2 * r) * 8 + oi];
            float w1 = Wl[(jbr * 32 + 2 * r + 1) * 8 + oi];
            float h0 = __uint_as_float(cvtpk(w0, w0) << 16);
            float h1 = __uint_as_float(cvtpk(w1, w1) << 16);
            float u0 = (lane < 32) ? w0 : (w0 - h0);
            float u1 = (lane < 32) ? w1 : (w1 - h1);
            t4[r] = cvtpk(u0, u1);
        }
        bw.x = t4[0]; bw.y = t4[1]; bw.z = t4[2]; bw.w = t4[3];
        Bfrag = __builtin_bit_cast(bf16x8, bw);
    }

    // ---- gl gather (antenna-major; plane layout) ----
    float g[8];
#pragma unroll
    for (int c = 0; c < 8; ++c) {
        float s = 0.f;
#pragma unroll
        for (int z = 0; z < NZ; ++z)
            s += gl_in[(((size_t)z * NB + b) * 8 + c) * NA + a];
        g[c] = s;
    }
    if (gl_skip) {
#pragma unroll
        for (int c = 0; c < 8; ++c) {
            float s = 0.f;
#pragma unroll
            for (int z = 0; z < NZ; ++z)
                s += gl_skip[(((size_t)z * NB + b) * 8 + c) * NA + a];
            g[c] = (g[c] + s) * 0.5f;
        }
    }
    // ---- cgl (antenna-major, fp32) -> LDS -> channel-lane C tiles ----
    {
        const v2f zero = v2f{0.f, 0.f};
        v2f cgl2[16];
#pragma unroll
        for (int i = 0; i < 16; ++i) cgl2[i] = zero;
#pragma unroll
        for (int c = 0; c < 8; ++c) {
            const v2f xx = v2f{g[c], g[c]};
#pragma unroll
            for (int j = 0; j < 4; ++j) {
                const v2f* wr = reinterpret_cast<const v2f*>(Wl + (j * 32 + 16 + c) * 8);
#pragma unroll
                for (int oi = 0; oi < 4; ++oi)
                    pk_fma_acc(cgl2[j * 4 + oi], xx, wr[oi]);
            }
        }
#pragma unroll
        for (int i = 0; i < 8; ++i)
            *reinterpret_cast<float4*>(&myl[lane * 36 + 4 * i]) =
                make_float4(cgl2[2*i].x, cgl2[2*i].y, cgl2[2*i+1].x, cgl2[2*i+1].y);
    }
    __syncthreads();
    f32x16 cT0, cT1;
#pragma unroll
    for (int r = 0; r < 16; ++r) {
        const int row = (r & 3) + 8 * (r >> 2) + h4;
        cT0[r] = myl[row * 36 + o];
        cT1[r] = myl[(32 + row) * 36 + o];
    }
    __syncthreads();   // cglT reads done before tb reuse (other wave's zeroing sync too)

    f32x16 acc0, acc1;
#pragma unroll
    for (int r = 0; r < 16; ++r) { acc0[r] = 0.f; acc1[r] = 0.f; }

    const unsigned short* llp =
        ll_in + (((size_t)(b * NU + uz * UN)) * NA + a) * 8;
    const size_t ustride = (size_t)NA * 8;
    uint4 xv = *reinterpret_cast<const uint4*>(llp);

#pragma unroll
    for (int k = 0; k < UN; ++k) {
        const int u = uz * UN + k;
        uint4 xnext = xv;
        if (k + 1 < UN)
            xnext = *reinterpret_cast<const uint4*>(llp + (size_t)(k + 1) * ustride);

        const float bse = base[(b * NU + u) * 32 + o];

        uint4 xs;
        xs.x = (unsigned)__shfl_xor((int)xv.x, 32, 64);
        xs.y = (unsigned)__shfl_xor((int)xv.y, 32, 64);
        xs.z = (unsigned)__shfl_xor((int)xv.z, 32, 64);
        xs.w = (unsigned)__shfl_xor((int)xv.w, 32, 64);
        const bool lo = lane < 32;
        uint4 a0u, a1u;
        a0u.x = lo ? xv.x : xs.x; a0u.y = lo ? xv.y : xs.y;
        a0u.z = lo ? xv.z : xs.z; a0u.w = lo ? xv.w : xs.w;
        a1u.x = lo ? xs.x : xv.x; a1u.y = lo ? xs.y : xv.y;
        a1u.z = lo ? xs.z : xv.z; a1u.w = lo ? xs.w : xv.w;
        bf16x8 A0 = __builtin_bit_cast(bf16x8, a0u);
        bf16x8 A1 = __builtin_bit_cast(bf16x8, a1u);

        f32x16 d0 = __builtin_amdgcn_mfma_f32_32x32x16_bf16(A0, Bfrag, cT0, 0, 0, 0);
        f32x16 d1 = __builtin_amdgcn_mfma_f32_32x32x16_bf16(A1, Bfrag, cT1, 0, 0, 0);
#pragma unroll
        for (int r = 0; r < 16; ++r) {
            d0[r] = __builtin_fmaxf(d0[r] + bse, 0.f);
            d1[r] = __builtin_fmaxf(d1[r] + bse, 0.f);
        }

        // lg (channels 8..15): rowsum over 64 antennas
        float red = treesum16(d0) + treesum16(d1);
        red += __shfl_xor(red, 32, 64);
        if (lane >= 8 && lane < 16) atomicAdd(&s_lg[k][lane - 8], red);

        // gl/gg accumulate over u
#pragma unroll
        for (int r = 0; r < 16; ++r) { acc0[r] += d0[r]; acc1[r] += d1[r]; }

        // transpose ch 0..7 to antenna-major via per-wave LDS [8][68]
        if (o < 8) {
#pragma unroll
            for (int q = 0; q < 4; ++q) {
                *reinterpret_cast<float4*>(&myl[o * 68 + q * 8 + h4]) =
                    make_float4(d0[4*q], d0[4*q+1], d0[4*q+2], d0[4*q+3]);
                *reinterpret_cast<float4*>(&myl[o * 68 + 32 + q * 8 + h4]) =
                    make_float4(d1[4*q], d1[4*q+1], d1[4*q+2], d1[4*q+3]);
            }
        }
        __syncthreads();
        float y[8];
#pragma unroll
        for (int c = 0; c < 8; ++c) y[c] = myl[c * 68 + lane];

        // skip paths (antenna-major, identical numerics to r7)
        const size_t xoff = (((size_t)(b * NU + u)) * NA + a) * 8;
        if (ll_skip) {
            float s[8];
            unpack8(*reinterpret_cast<const uint4*>(ll_skip + xoff), s);
#pragma unroll
            for (int c = 0; c < 8; ++c) y[c] = (y[c] + s[c]) * 0.5f;
        } else if (ch) {
            float xc[4];
#pragma unroll
            for (int c = 0; c < 4; ++c)
                xc[c] = ch[(((size_t)b * 4 + c) * NU + u) * NA + a];
            float s[8];
#pragma unroll
            for (int i = 0; i < 8; ++i) s[i] = b1[i];
#pragma unroll
            for (int c = 0; c < 4; ++c)
#pragma unroll
                for (int i = 0; i < 8; ++i)
                    s[i] = fmaf(xc[c], W1[c * 8 + i], s[i]);
#pragma unroll
            for (int i = 0; i < 8; ++i)
                y[i] = (y[i] + __builtin_fmaxf(s[i], 0.f)) * 0.5f;
        }
        store8f(ll_out + xoff, y);
        __syncthreads();   // reads done before next-iter tb writes (paranoia, cheap)
        xv = xnext;
    }

    // gg: raw rowsum (consumer divides by 16384)
    float gr = treesum16(acc0) + treesum16(acc1);
    gr += __shfl_xor(gr, 32, 64);
    if (lane >= 24 && lane < 32) atomicAdd(&s_gg[lane - 24], gr);

    // gl store (channels 16..23), plane layout, scaled 1/U
    if (o >= 16 && o < 24) {
        const float invU = 1.f / 16.f;
        const int wbase = blockIdx.y * 128 + (tid & 64);
        float* gp = gl_out + (((size_t)uz * NB + b) * 8 + (o - 16)) * NA + wbase + h4;
#pragma unroll
        for (int q = 0; q < 4; ++q) {
            *reinterpret_cast<float4*>(gp + q * 8) =
                make_float4(acc0[4*q]*invU, acc0[4*q+1]*invU, acc0[4*q+2]*invU, acc0[4*q+3]*invU);
            *reinterpret_cast<float4*>(gp + 32 + q * 8) =
                make_float4(acc1[4*q]*invU, acc1[4*q+1]*invU, acc1[4*q+2]*invU, acc1[4*q+3]*invU);
        }
    }
    __syncthreads();
    if (tid < UN * 8)
        atomicAdd(lg_out + ((size_t)b * NU + uz * UN + (tid >> 3)) * 8 + (tid & 7),
                  s_lg[tid >> 3][tid & 7]);
    if (tid >= 64 && tid < 72)
        atomicAdd(gg_out + b * 8 + (tid & 7), s_gg[tid & 7]);
}

// ---------------- Layer 8 (gl reads -> plane layout) ----------------
template <int NZ>
__global__ __launch_bounds__(128) void layer_out_t(
    const unsigned short* __restrict__ ll,
    const float* __restrict__ lg7, const float* __restrict__ lg3,
    const float* __restrict__ gl7, const float* __restrict__ gl3,
    const float* __restrict__ gg7, const float* __restrict__ gg3,
    const float* __restrict__ W8, const float* __restrict__ b8,
    float* __restrict__ out)
{
    constexpr int UN = NU / NZ;
    const int b = blockIdx.x;
    const int a = blockIdx.y * 128 + threadIdx.x;
    const int uz = blockIdx.z;
    const float invA = 1.f / 1024.f, invUA = 1.f / 16384.f, invU = 1.f / 16.f;

    float acc = 0.f;
#pragma unroll
    for (int k = 0; k < UN; ++k) {
        const int u = uz * UN + k;
        float x[8];
        unpack8(*reinterpret_cast<const uint4*>(
            ll + (((size_t)(b * NU + u)) * NA + a) * 8), x);
#pragma unroll
        for (int c = 0; c < 8; ++c) acc += x[c] * W8[c];
    }
    acc *= invU;

    if (uz == 0) {
        float sb = b8[0];
#pragma unroll
        for (int c = 0; c < 8; ++c) {
            float s7 = 0.f, s3 = 0.f;
#pragma unroll
            for (int u = 0; u < NU; ++u) {
                s7 += lg7[(b * NU + u) * 8 + c];
                s3 += lg3[(b * NU + u) * 8 + c];
            }
            sb += ((s7 * invA + s3 * invA) * 0.5f * invU) * W8[8 + c];
        }
#pragma unroll
        for (int c = 0; c < 8; ++c)
            sb += ((gg7[b * 8 + c] + gg3[b * 8 + c]) * invUA * 0.5f) * W8[24 + c];

        float s7[8], s3[8];
#pragma unroll
        for (int i = 0; i < 8; ++i) { s7[i] = 0.f; s3[i] = 0.f; }
#pragma unroll
        for (int z = 0; z < NZ; ++z)
#pragma unroll
            for (int i = 0; i < 8; ++i) {
                s7[i] += gl7[(((size_t)z * NB + b) * 8 + i) * NA + a];
                s3[i] += gl3[(((size_t)z * NB + b) * 8 + i) * NA + a];
            }
#pragma unroll
        for (int i = 0; i < 8; ++i)
            acc += 0.5f * (s7[i] + s3[i]) * W8[16 + i];
        acc += sb;
    }
    atomicAdd(out + (size_t)b * NA + a, acc * PI_F);
}

// ---------------- host ----------------
static constexpr size_t LLsz = (size_t)NB * NU * NA * 8;
static constexpr size_t GLsz = (size_t)NB * NA * 8;
static constexpr size_t LGsz = (size_t)NB * NU * 8;
static constexpr size_t GGsz = (size_t)NB * 8;

template <int NZ>
static void run_pipeline(const float* channel, const float* W1, const float* b1,
                         const float* Wm, const float* bm, const float* W8,
                         const float* b8, float* out, int out_bytes,
                         void* d_ws, hipStream_t stream)
{
    unsigned short* cur = (unsigned short*)d_ws;
    unsigned short* f3s = cur + LLsz;
    float* glb = (float*)(f3s + LLsz);
    float* g0 = glb;
    float* g1 = glb + (size_t)NZ * GLsz;
    float* g2 = glb + (size_t)2 * NZ * GLsz;
    float* g3 = glb + (size_t)3 * NZ * GLsz;
    float* lgb = glb + (size_t)4 * NZ * GLsz;
    float* ggb = lgb + 7 * LGsz;
    float* base = ggb + 7 * GGsz;

    hipMemsetAsync(lgb, 0, (7 * LGsz + 7 * GGsz) * sizeof(float), stream);
    hipMemsetAsync(out, 0, out_bytes, stream);

    dim3 grid(NB, NA / 128, NZ), blk(128);

    layer_first_t<NZ><<<grid, blk, 0, stream>>>(channel, W1, b1, cur, lgb, g0, ggb);

    prep_base_k<<<8, 256, 0, stream>>>(lgb, nullptr, ggb, nullptr, Wm, bm, base);
    layer_main_t<NZ><<<grid, blk, 0, stream>>>(cur, g0, nullptr, base, Wm,
        nullptr, nullptr, nullptr, nullptr,
        cur, lgb + 1 * LGsz, g2, ggb + 1 * GGsz);

    prep_base_k<<<8, 256, 0, stream>>>(lgb + 1 * LGsz, nullptr, ggb + 1 * GGsz, nullptr,
                                       Wm + 1024, bm + 32, base);
    layer_main_t<NZ><<<grid, blk, 0, stream>>>(cur, g2, nullptr, base, Wm + 1024,
        nullptr, nullptr, nullptr, nullptr,
        f3s, lgb + 2 * LGsz, g1, ggb + 2 * GGsz);

    prep_base_k<<<8, 256, 0, stream>>>(lgb + 2 * LGsz, nullptr, ggb + 2 * GGsz, nullptr,
                                       Wm + 2048, bm + 64, base);
    layer_main_t<NZ><<<grid, blk, 0, stream>>>(f3s, g1, nullptr, base, Wm + 2048,
        nullptr, nullptr, nullptr, nullptr,
        cur, lgb + 3 * LGsz, g3, ggb + 3 * GGsz);

    prep_base_k<<<8, 256, 0, stream>>>(lgb + 3 * LGsz, nullptr, ggb + 3 * GGsz, nullptr,
                                       Wm + 3072, bm + 96, base);
    layer_main_t<NZ><<<grid, blk, 0, stream>>>(cur, g3, nullptr, base, Wm + 3072,
        nullptr, channel, W1, b1,
        cur, lgb + 4 * LGsz, g2, ggb + 4 * GGsz);

    prep_base_k<<<8, 256, 0, stream>>>(lgb + 4 * LGsz, lgb, ggb + 4 * GGsz, ggb,
                                       Wm + 4096, bm + 128, base);
    layer_main_t<NZ><<<grid, blk, 0, stream>>>(cur, g2, g0, base, Wm + 4096,
        nullptr, nullptr, nullptr, nullptr,
        cur, lgb + 5 * LGsz, g3, ggb + 5 * GGsz);

    prep_base_k<<<8, 256, 0, stream>>>(lgb + 5 * LGsz, nullptr, ggb + 5 * GGsz, nullptr,
                                       Wm + 5120, bm + 160, base);
    layer_main_t<NZ><<<grid, blk, 0, stream>>>(cur, g3, nullptr, base, Wm + 5120,
        f3s, nullptr, nullptr, nullptr,
        cur, lgb + 6 * LGsz, g2, ggb + 6 * GGsz);

    layer_out_t<NZ><<<grid, blk, 0, stream>>>(cur, lgb + 6 * LGsz, lgb + 2 * LGsz,
                                              g2, g1, ggb + 6 * GGsz, ggb + 2 * GGsz,
                                              W8, b8, out);
}

static size_t ws_req(int nz) {
    return LLsz * 2 * sizeof(unsigned short)
         + (size_t)4 * nz * GLsz * sizeof(float)
         + (7 * LGsz + 7 * GGsz + 2048 * 32) * sizeof(float);
}

extern "C" void kernel_launch(void* const* d_in, const int* in_sizes, int n_in,
                              void* d_out, int out_size, void* d_ws, size_t ws_size,
                              hipStream_t stream) {
    const float* channel = (const float*)d_in[0];
    const float* W1 = (const float*)d_in[1];
    const float* b1 = (const float*)d_in[2];
    const float* Wm = (const float*)d_in[3];
    const float* bm = (const float*)d_in[4];
    const float* W8 = (const float*)d_in[5];
    const float* b8 = (const float*)d_in[6];
    float* out = (float*)d_out;

    if (ws_size >= ws_req(4)) {
        run_pipeline<4>(channel, W1, b1, Wm, bm, W8, b8, out, out_size, d_ws, stream);
    } else if (ws_size >= ws_req(2)) {
        run_pipeline<2>(channel, W1, b1, Wm, bm, W8, b8, out, out_size, d_ws, stream);
    } else {
        run_pipeline<1>(channel, W1, b1, Wm, bm, W8, b8, out, out_size, d_ws, stream);
    }
}

// Round 10
// 403.043 us; speedup vs baseline: 1.0764x; 1.0335x over previous
//
#include <hip/hip_runtime.h>

// RISnetPIv2: B=128, U=16, A=1024, FEAT=4, INFO=8.
// Round-10: r9 MFMA structure (416us, passed) with the stall axes removed:
//  - 64-thr single-wave blocks: the per-u LDS transpose is wave-local, so
//    __syncthreads is free (r9 paid 2 cross-wave barriers per u at 16% occ).
//  - pair-tiling: wave = 32 antennas x 2 users/iter (lanes 0-31 = u,
//    32-63 = u+1; same shfl_xor(32) A-build as r9, reinterpreted). cT and
//    the gl/gg accumulator are shared by both tiles -> 32 fewer VGPRs;
//    LDS 18.9KB -> 4.7KB.
// B-fragment K-split (W + W-residual, ~2^-17 weight precision) and all
// layouts carried unchanged from r9 (HW-verified by r9's pass).

#define NB 128
#define NU 16
#define NA 1024

typedef float v2f __attribute__((ext_vector_type(2)));
typedef __attribute__((ext_vector_type(8))) short bf16x8;
typedef __attribute__((ext_vector_type(16))) float f32x16;

static constexpr float PI_F = 3.14159265358979323846f;

__device__ __forceinline__ void pk_fma_acc(v2f& acc, v2f a, v2f b) {
    asm("v_pk_fma_f32 %0, %1, %2, %0" : "+v"(acc) : "v"(a), "v"(b));
}
__device__ __forceinline__ unsigned int cvtpk(float a, float b) {
    unsigned int r;
    asm("v_cvt_pk_bf16_f32 %0, %1, %2" : "=v"(r) : "v"(a), "v"(b));
    return r;  // lo = bf16(a), hi = bf16(b), RNE
}
__device__ __forceinline__ void unpack8(uint4 v, float x[8]) {
    x[0] = __uint_as_float(v.x << 16); x[1] = __uint_as_float(v.x & 0xffff0000u);
    x[2] = __uint_as_float(v.y << 16); x[3] = __uint_as_float(v.y & 0xffff0000u);
    x[4] = __uint_as_float(v.z << 16); x[5] = __uint_as_float(v.z & 0xffff0000u);
    x[6] = __uint_as_float(v.w << 16); x[7] = __uint_as_float(v.w & 0xffff0000u);
}
__device__ __forceinline__ void store8f(unsigned short* p, const float y[8]) {
    uint4 v;
    v.x = cvtpk(y[0], y[1]); v.y = cvtpk(y[2], y[3]);
    v.z = cvtpk(y[4], y[5]); v.w = cvtpk(y[6], y[7]);
    *reinterpret_cast<uint4*>(p) = v;
}
__device__ __forceinline__ float treesum16(f32x16 v) {
    float a0 = v[0] + v[1], a1 = v[2] + v[3], a2 = v[4] + v[5], a3 = v[6] + v[7];
    float a4 = v[8] + v[9], a5 = v[10] + v[11], a6 = v[12] + v[13], a7 = v[14] + v[15];
    float b0 = a0 + a1, b1 = a2 + a3, b2 = a4 + a5, b3 = a6 + a7;
    return (b0 + b1) + (b2 + b3);
}

// 3-level channel-merging butterfly (layer_first only, proven r7/r9)
__device__ __forceinline__ float merge3v(const v2f* y, int lane) {
    float w[4];
    const bool s0 = (lane & 1) != 0;
#pragma unroll
    for (int k = 0; k < 4; ++k) {
        float lo = s0 ? y[k].y : y[k].x;
        float hi = s0 ? y[k].x : y[k].y;
        w[k] = lo + __shfl_xor(hi, 1, 64);
    }
    const bool s1 = (lane & 2) != 0;
#pragma unroll
    for (int k = 0; k < 2; ++k) {
        float lo = s1 ? w[2 * k + 1] : w[2 * k];
        float hi = s1 ? w[2 * k] : w[2 * k + 1];
        w[k] = lo + __shfl_xor(hi, 2, 64);
    }
    const bool s2 = (lane & 4) != 0;
    float lo = s2 ? w[1] : w[0];
    float hi = s2 ? w[0] : w[1];
    return lo + __shfl_xor(hi, 4, 64);
}

// ---------------- Layer 1 (VALU; gl -> plane layout) — unchanged from r9 ----
template <int NZ>
__global__ __launch_bounds__(128) void layer_first_t(
    const float* __restrict__ ch, const float* __restrict__ W1,
    const float* __restrict__ b1, unsigned short* __restrict__ ll_out,
    float* __restrict__ lg_out, float* __restrict__ gl_out,
    float* __restrict__ gg_out)
{
    constexpr int UN = NU / NZ;
    const int b = blockIdx.x;
    const int a = blockIdx.y * 128 + threadIdx.x;
    const int uz = blockIdx.z;
    const int lane = threadIdx.x & 63;
    const int tid = threadIdx.x;

    __shared__ float s_lg[UN][8];
    __shared__ float s_gg[8];
    if (tid < UN * 8) s_lg[tid >> 3][tid & 7] = 0.f;
    if (tid >= 64 && tid < 72) s_gg[tid & 7] = 0.f;
    __syncthreads();

    v2f glacc2[4], ggacc2[4];
#pragma unroll
    for (int i = 0; i < 4; ++i) { glacc2[i] = v2f{0.f, 0.f}; ggacc2[i] = v2f{0.f, 0.f}; }

#pragma unroll
    for (int k = 0; k < UN; ++k) {
        const int u = uz * UN + k;
        float x[4];
#pragma unroll
        for (int c = 0; c < 4; ++c)
            x[c] = ch[(((size_t)b * 4 + c) * NU + u) * NA + a];

        v2f y2[16];
        const v2f* b2 = reinterpret_cast<const v2f*>(b1);
#pragma unroll
        for (int o = 0; o < 16; ++o) y2[o] = b2[o];
#pragma unroll
        for (int c = 0; c < 4; ++c) {
            const v2f xx = v2f{x[c], x[c]};
#pragma unroll
            for (int j = 0; j < 4; ++j) {
                const v2f* wr = reinterpret_cast<const v2f*>(W1 + (j * 4 + c) * 8);
#pragma unroll
                for (int oi = 0; oi < 4; ++oi)
                    pk_fma_acc(y2[j * 4 + oi], xx, wr[oi]);
            }
        }
#pragma unroll
        for (int o = 0; o < 16; ++o)
            y2[o] = v2f{__builtin_fmaxf(y2[o].x, 0.f), __builtin_fmaxf(y2[o].y, 0.f)};

        const size_t xoff = (((size_t)(b * NU + u)) * NA + a) * 8;
        {
            uint4 v;
            v.x = cvtpk(y2[0].x, y2[0].y); v.y = cvtpk(y2[1].x, y2[1].y);
            v.z = cvtpk(y2[2].x, y2[2].y); v.w = cvtpk(y2[3].x, y2[3].y);
            *reinterpret_cast<uint4*>(ll_out + xoff) = v;
        }
#pragma unroll
        for (int i = 0; i < 4; ++i) {
            glacc2[i] += y2[8 + i];
            ggacc2[i] += y2[12 + i];
        }
        float lr = merge3v(y2 + 4, lane);
        atomicAdd(&s_lg[k][lane & 7], lr);
    }
    {   // gl partial, channel-plane layout [uz][b][c][a]
        const float invU = 1.f / 16.f;
        float ga[8];
#pragma unroll
        for (int i = 0; i < 4; ++i) { ga[2*i] = glacc2[i].x; ga[2*i+1] = glacc2[i].y; }
#pragma unroll
        for (int c = 0; c < 8; ++c)
            gl_out[(((size_t)uz * NB + b) * 8 + c) * NA + a] = ga[c] * invU;
    }
    float gga[8];
#pragma unroll
    for (int i = 0; i < 4; ++i) { gga[2*i] = ggacc2[i].x; gga[2*i+1] = ggacc2[i].y; }
    float gr = merge3v(reinterpret_cast<const v2f*>(gga), lane);
    atomicAdd(&s_gg[lane & 7], gr);
    __syncthreads();
    if (tid < UN * 8)
        atomicAdd(lg_out + ((size_t)b * NU + uz * UN + (tid >> 3)) * 8 + (tid & 7),
                  s_lg[tid >> 3][tid & 7]);
    if (tid >= 64 && tid < 72)
        atomicAdd(gg_out + b * 8 + (tid & 7), s_gg[tid & 7]);
}

// -------- prep: base[b,u,32] = bias + lg·W_lg + gg·W_gg (unchanged) --------
__global__ __launch_bounds__(256) void prep_base_k(
    const float* __restrict__ lg_sum, const float* __restrict__ lg_skip,
    const float* __restrict__ gg_sum, const float* __restrict__ gg_skip,
    const float* __restrict__ Wl, const float* __restrict__ bl,
    float* __restrict__ base)
{
    const int t = blockIdx.x * 256 + threadIdx.x;  // b*16+u
    if (t >= NB * NU) return;
    const int b = t >> 4;
    const float invA = 1.f / 1024.f, invUA = 1.f / 16384.f;
    float lg[8], gg[8];
#pragma unroll
    for (int c = 0; c < 8; ++c) {
        float v = lg_sum[t * 8 + c] * invA;
        if (lg_skip) v = (v + lg_skip[t * 8 + c] * invA) * 0.5f;
        lg[c] = v;
    }
#pragma unroll
    for (int c = 0; c < 8; ++c) {
        float v = gg_sum[b * 8 + c] * invUA;
        if (gg_skip) v = (v + gg_skip[b * 8 + c] * invUA) * 0.5f;
        gg[c] = v;
    }
    float y[32];
#pragma unroll
    for (int o = 0; o < 32; ++o) y[o] = bl[o];
#pragma unroll
    for (int j = 0; j < 4; ++j)
#pragma unroll
        for (int c = 0; c < 8; ++c) {
            const float* wl = Wl + (j * 32 + 8 + c) * 8;
            const float* wg = Wl + (j * 32 + 24 + c) * 8;
#pragma unroll
            for (int oi = 0; oi < 8; ++oi) {
                y[j * 8 + oi] = fmaf(lg[c], wl[oi], y[j * 8 + oi]);
                y[j * 8 + oi] = fmaf(gg[c], wg[oi], y[j * 8 + oi]);
            }
        }
#pragma unroll
    for (int o = 0; o < 32; ++o) base[t * 32 + o] = y[o];
}

// ---------------- Layers 2..7: MFMA, single-wave, pair-tiled ----------------
// Wave = 32 antennas x 2 users per iteration. Lanes 0-31 carry user u0,
// lanes 32-63 carry u0+1. d0 = u0 tile (32 ant x 32 ch), d1 = u0+1 tile.
// In-place safe: each lane stores the exact row it loaded; blocks own
// disjoint (b, antenna-window, uz-slice).
template <int NZ>
__global__ __launch_bounds__(64) void layer_main_t(
    const unsigned short* ll_in, const float* __restrict__ gl_in,
    const float* __restrict__ gl_skip, const float* __restrict__ base,
    const float* __restrict__ Wl,
    const unsigned short* __restrict__ ll_skip,          // layer 7: f3 ll
    const float* __restrict__ ch, const float* __restrict__ W1,
    const float* __restrict__ b1,                        // layer 5: recompute f1
    unsigned short* ll_out, float* __restrict__ lg_out,
    float* __restrict__ gl_out, float* __restrict__ gg_out)
{
    constexpr int UN = NU / NZ;
    const int b = blockIdx.x;
    const int lane = threadIdx.x;       // 0..63
    const int o = lane & 31;            // channel col in D space / antenna id
    const int h4 = 4 * (lane >> 5);
    const int half = lane >> 5;         // u-offset within pair
    const int a32 = blockIdx.y * 32 + o;
    const int uz = blockIdx.z;

    __shared__ float s_lg[UN][8];
    __shared__ float s_gg[8];
    __shared__ float myl[32 * 36];      // cglT staging [32][36]; reused as tb [8][68]
    for (int t = lane; t < UN * 8; t += 64) s_lg[t >> 3][t & 7] = 0.f;
    if (lane < 8) s_gg[lane] = 0.f;

    // ---- B fragment (r9-verified): col o; k0-7 = bf16(W), k8-15 = residual --
    bf16x8 Bfrag;
    {
        const int jbr = o >> 3, oi = o & 7;
        uint4 bw;
        unsigned int t4[4];
#pragma unroll
        for (int r = 0; r < 4; ++r) {
            float w0 = Wl[(jbr * 32 + 2 * r) * 8 + oi];
            float w1 = Wl[(jbr * 32 + 2 * r + 1) * 8 + oi];
            float h0 = __uint_as_float(cvtpk(w0, w0) << 16);
            float h1 = __uint_as_float(cvtpk(w1, w1) << 16);
            float u0 = (lane < 32) ? w0 : (w0 - h0);
            float u1 = (lane < 32) ? w1 : (w1 - h1);
            t4[r] = cvtpk(u0, u1);
        }
        bw.x = t4[0]; bw.y = t4[1]; bw.z = t4[2]; bw.w = t4[3];
        Bfrag = __builtin_bit_cast(bf16x8, bw);
    }

    // ---- cgl for this block's 32 antennas (lanes 0-31), staged to LDS ----
    if (lane < 32) {
        float g[8];
#pragma unroll
        for (int c = 0; c < 8; ++c) {
            float s = 0.f;
#pragma unroll
            for (int z = 0; z < NZ; ++z)
                s += gl_in[(((size_t)z * NB + b) * 8 + c) * NA + a32];
            g[c] = s;
        }
        if (gl_skip) {
#pragma unroll
            for (int c = 0; c < 8; ++c) {
                float s = 0.f;
#pragma unroll
                for (int z = 0; z < NZ; ++z)
                    s += gl_skip[(((size_t)z * NB + b) * 8 + c) * NA + a32];
                g[c] = (g[c] + s) * 0.5f;
            }
        }
        v2f cgl2[16];
#pragma unroll
        for (int i = 0; i < 16; ++i) cgl2[i] = v2f{0.f, 0.f};
#pragma unroll
        for (int c = 0; c < 8; ++c) {
            const v2f xx = v2f{g[c], g[c]};
#pragma unroll
            for (int j = 0; j < 4; ++j) {
                const v2f* wr = reinterpret_cast<const v2f*>(Wl + (j * 32 + 16 + c) * 8);
#pragma unroll
                for (int oi = 0; oi < 4; ++oi)
                    pk_fma_acc(cgl2[j * 4 + oi], xx, wr[oi]);
            }
        }
#pragma unroll
        for (int i = 0; i < 8; ++i)
            *reinterpret_cast<float4*>(&myl[lane * 36 + 4 * i]) =
                make_float4(cgl2[2*i].x, cgl2[2*i].y, cgl2[2*i+1].x, cgl2[2*i+1].y);
    }
    __syncthreads();     // single wave: compiles to waitcnt only
    f32x16 cT;
#pragma unroll
    for (int r = 0; r < 16; ++r) {
        const int row = (r & 3) + 8 * (r >> 2) + h4;
        cT[r] = myl[row * 36 + o];
    }
    __syncthreads();     // cglT reads done before tb reuse

    f32x16 acc;
#pragma unroll
    for (int r = 0; r < 16; ++r) acc[r] = 0.f;

    // per-lane row pointer: user = uz*UN + half, antenna a32
    const unsigned short* llrow =
        ll_in + (((size_t)(b * NU + uz * UN + half)) * NA + a32) * 8;
    const size_t pstride = (size_t)2 * NA * 8;    // pair stride (2 users)
    uint4 xv = *reinterpret_cast<const uint4*>(llrow);

#pragma unroll
    for (int kp = 0; kp < UN / 2; ++kp) {
        const int u0 = uz * UN + 2 * kp;
        uint4 xnext = xv;
        if (kp + 1 < UN / 2)
            xnext = *reinterpret_cast<const uint4*>(llrow + (size_t)(kp + 1) * pstride);

        const float bse0 = base[(b * NU + u0) * 32 + o];
        const float bse1 = base[(b * NU + u0 + 1) * 32 + o];

        uint4 xs;
        xs.x = (unsigned)__shfl_xor((int)xv.x, 32, 64);
        xs.y = (unsigned)__shfl_xor((int)xv.y, 32, 64);
        xs.z = (unsigned)__shfl_xor((int)xv.z, 32, 64);
        xs.w = (unsigned)__shfl_xor((int)xv.w, 32, 64);
        const bool lo = lane < 32;
        uint4 a0u, a1u;
        a0u.x = lo ? xv.x : xs.x; a0u.y = lo ? xv.y : xs.y;
        a0u.z = lo ? xv.z : xs.z; a0u.w = lo ? xv.w : xs.w;
        a1u.x = lo ? xs.x : xv.x; a1u.y = lo ? xs.y : xv.y;
        a1u.z = lo ? xs.z : xv.z; a1u.w = lo ? xs.w : xv.w;
        bf16x8 A0 = __builtin_bit_cast(bf16x8, a0u);
        bf16x8 A1 = __builtin_bit_cast(bf16x8, a1u);

        f32x16 d0 = __builtin_amdgcn_mfma_f32_32x32x16_bf16(A0, Bfrag, cT, 0, 0, 0);
        f32x16 d1 = __builtin_amdgcn_mfma_f32_32x32x16_bf16(A1, Bfrag, cT, 0, 0, 0);
#pragma unroll
        for (int r = 0; r < 16; ++r) {
            d0[r] = __builtin_fmaxf(d0[r] + bse0, 0.f);
            d1[r] = __builtin_fmaxf(d1[r] + bse1, 0.f);
        }

        // lg (channels 8..15): per-u rowsum over the 32 antennas
        float red0 = treesum16(d0);
        red0 += __shfl_xor(red0, 32, 64);
        if (lane >= 8 && lane < 16) atomicAdd(&s_lg[2 * kp][lane - 8], red0);
        float red1 = treesum16(d1);
        red1 += __shfl_xor(red1, 32, 64);
        if (lane >= 8 && lane < 16) atomicAdd(&s_lg[2 * kp + 1][lane - 8], red1);

        // gl/gg accumulate (both users into one acc)
#pragma unroll
        for (int r = 0; r < 16; ++r) acc[r] += d0[r] + d1[r];

        // transpose ch0-7 of both users: tb[c][ant + 32*half] (cols = lane id)
        if (o < 8) {
#pragma unroll
            for (int q = 0; q < 4; ++q) {
                *reinterpret_cast<float4*>(&myl[o * 68 + q * 8 + h4]) =
                    make_float4(d0[4*q], d0[4*q+1], d0[4*q+2], d0[4*q+3]);
                *reinterpret_cast<float4*>(&myl[o * 68 + 32 + q * 8 + h4]) =
                    make_float4(d1[4*q], d1[4*q+1], d1[4*q+2], d1[4*q+3]);
            }
        }
        __syncthreads();
        float y[8];
#pragma unroll
        for (int c = 0; c < 8; ++c) y[c] = myl[c * 68 + lane];

        // skip paths (antenna-major; per-lane user u0+half)
        const int u_lane = u0 + half;
        const size_t xoff = (((size_t)(b * NU + u_lane)) * NA + a32) * 8;
        if (ll_skip) {
            float s[8];
            unpack8(*reinterpret_cast<const uint4*>(ll_skip + xoff), s);
#pragma unroll
            for (int c = 0; c < 8; ++c) y[c] = (y[c] + s[c]) * 0.5f;
        } else if (ch) {
            float xc[4];
#pragma unroll
            for (int c = 0; c < 4; ++c)
                xc[c] = ch[(((size_t)b * 4 + c) * NU + u_lane) * NA + a32];
            float s[8];
#pragma unroll
            for (int i = 0; i < 8; ++i) s[i] = b1[i];
#pragma unroll
            for (int c = 0; c < 4; ++c)
#pragma unroll
                for (int i = 0; i < 8; ++i)
                    s[i] = fmaf(xc[c], W1[c * 8 + i], s[i]);
#pragma unroll
            for (int i = 0; i < 8; ++i)
                y[i] = (y[i] + __builtin_fmaxf(s[i], 0.f)) * 0.5f;
        }
        store8f(ll_out + xoff, y);
        __syncthreads();    // tb reads done before next pair's writes
        xv = xnext;
    }

    // gg: total rowsum (consumer divides by 16384)
    float gr = treesum16(acc);
    gr += __shfl_xor(gr, 32, 64);
    if (lane >= 24 && lane < 32) atomicAdd(&s_gg[lane - 24], gr);

    // gl store (channels 16..23), plane layout, scaled 1/U
    if (o >= 16 && o < 24) {
        const float invU = 1.f / 16.f;
        float* gp = gl_out + (((size_t)uz * NB + b) * 8 + (o - 16)) * NA
                  + blockIdx.y * 32;
#pragma unroll
        for (int q = 0; q < 4; ++q)
            *reinterpret_cast<float4*>(gp + q * 8 + h4) =
                make_float4(acc[4*q]*invU, acc[4*q+1]*invU, acc[4*q+2]*invU, acc[4*q+3]*invU);
    }
    __syncthreads();
    for (int t = lane; t < UN * 8; t += 64)
        atomicAdd(lg_out + ((size_t)b * NU + uz * UN + (t >> 3)) * 8 + (t & 7),
                  s_lg[t >> 3][t & 7]);
    if (lane < 8)
        atomicAdd(gg_out + b * 8 + lane, s_gg[lane]);
}

// ---------------- Layer 8 (gl plane layout) — unchanged from r9 ----------------
template <int NZ>
__global__ __launch_bounds__(128) void layer_out_t(
    const unsigned short* __restrict__ ll,
    const float* __restrict__ lg7, const float* __restrict__ lg3,
    const float* __restrict__ gl7, const float* __restrict__ gl3,
    const float* __restrict__ gg7, const float* __restrict__ gg3,
    const float* __restrict__ W8, const float* __restrict__ b8,
    float* __restrict__ out)
{
    constexpr int UN = NU / NZ;
    const int b = blockIdx.x;
    const int a = blockIdx.y * 128 + threadIdx.x;
    const int uz = blockIdx.z;
    const float invA = 1.f / 1024.f, invUA = 1.f / 16384.f, invU = 1.f / 16.f;

    float acc = 0.f;
#pragma unroll
    for (int k = 0; k < UN; ++k) {
        const int u = uz * UN + k;
        float x[8];
        unpack8(*reinterpret_cast<const uint4*>(
            ll + (((size_t)(b * NU + u)) * NA + a) * 8), x);
#pragma unroll
        for (int c = 0; c < 8; ++c) acc += x[c] * W8[c];
    }
    acc *= invU;

    if (uz == 0) {
        float sb = b8[0];
#pragma unroll
        for (int c = 0; c < 8; ++c) {
            float s7 = 0.f, s3 = 0.f;
#pragma unroll
            for (int u = 0; u < NU; ++u) {
                s7 += lg7[(b * NU + u) * 8 + c];
                s3 += lg3[(b * NU + u) * 8 + c];
            }
            sb += ((s7 * invA + s3 * invA) * 0.5f * invU) * W8[8 + c];
        }
#pragma unroll
        for (int c = 0; c < 8; ++c)
            sb += ((gg7[b * 8 + c] + gg3[b * 8 + c]) * invUA * 0.5f) * W8[24 + c];

        float s7[8], s3[8];
#pragma unroll
        for (int i = 0; i < 8; ++i) { s7[i] = 0.f; s3[i] = 0.f; }
#pragma unroll
        for (int z = 0; z < NZ; ++z)
#pragma unroll
            for (int i = 0; i < 8; ++i) {
                s7[i] += gl7[(((size_t)z * NB + b) * 8 + i) * NA + a];
                s3[i] += gl3[(((size_t)z * NB + b) * 8 + i) * NA + a];
            }
#pragma unroll
        for (int i = 0; i < 8; ++i)
            acc += 0.5f * (s7[i] + s3[i]) * W8[16 + i];
        acc += sb;
    }
    atomicAdd(out + (size_t)b * NA + a, acc * PI_F);
}

// ---------------- host ----------------
static constexpr size_t LLsz = (size_t)NB * NU * NA * 8;
static constexpr size_t GLsz = (size_t)NB * NA * 8;
static constexpr size_t LGsz = (size_t)NB * NU * 8;
static constexpr size_t GGsz = (size_t)NB * 8;

template <int NZ>
static void run_pipeline(const float* channel, const float* W1, const float* b1,
                         const float* Wm, const float* bm, const float* W8,
                         const float* b8, float* out, int out_bytes,
                         void* d_ws, hipStream_t stream)
{
    unsigned short* cur = (unsigned short*)d_ws;
    unsigned short* f3s = cur + LLsz;
    float* glb = (float*)(f3s + LLsz);
    float* g0 = glb;
    float* g1 = glb + (size_t)NZ * GLsz;
    float* g2 = glb + (size_t)2 * NZ * GLsz;
    float* g3 = glb + (size_t)3 * NZ * GLsz;
    float* lgb = glb + (size_t)4 * NZ * GLsz;
    float* ggb = lgb + 7 * LGsz;
    float* base = ggb + 7 * GGsz;

    hipMemsetAsync(lgb, 0, (7 * LGsz + 7 * GGsz) * sizeof(float), stream);
    hipMemsetAsync(out, 0, out_bytes, stream);

    dim3 gridF(NB, NA / 128, NZ), blkF(128);
    dim3 gridM(NB, NA / 32, NZ), blkM(64);

    layer_first_t<NZ><<<gridF, blkF, 0, stream>>>(channel, W1, b1, cur, lgb, g0, ggb);

    prep_base_k<<<8, 256, 0, stream>>>(lgb, nullptr, ggb, nullptr, Wm, bm, base);
    layer_main_t<NZ><<<gridM, blkM, 0, stream>>>(cur, g0, nullptr, base, Wm,
        nullptr, nullptr, nullptr, nullptr,
        cur, lgb + 1 * LGsz, g2, ggb + 1 * GGsz);

    prep_base_k<<<8, 256, 0, stream>>>(lgb + 1 * LGsz, nullptr, ggb + 1 * GGsz, nullptr,
                                       Wm + 1024, bm + 32, base);
    layer_main_t<NZ><<<gridM, blkM, 0, stream>>>(cur, g2, nullptr, base, Wm + 1024,
        nullptr, nullptr, nullptr, nullptr,
        f3s, lgb + 2 * LGsz, g1, ggb + 2 * GGsz);

    prep_base_k<<<8, 256, 0, stream>>>(lgb + 2 * LGsz, nullptr, ggb + 2 * GGsz, nullptr,
                                       Wm + 2048, bm + 64, base);
    layer_main_t<NZ><<<gridM, blkM, 0, stream>>>(f3s, g1, nullptr, base, Wm + 2048,
        nullptr, nullptr, nullptr, nullptr,
        cur, lgb + 3 * LGsz, g3, ggb + 3 * GGsz);

    prep_base_k<<<8, 256, 0, stream>>>(lgb + 3 * LGsz, nullptr, ggb + 3 * GGsz, nullptr,
                                       Wm + 3072, bm + 96, base);
    layer_main_t<NZ><<<gridM, blkM, 0, stream>>>(cur, g3, nullptr, base, Wm + 3072,
        nullptr, channel, W1, b1,
        cur, lgb + 4 * LGsz, g2, ggb + 4 * GGsz);

    prep_base_k<<<8, 256, 0, stream>>>(lgb + 4 * LGsz, lgb, ggb + 4 * GGsz, ggb,
                                       Wm + 4096, bm + 128, base);
    layer_main_t<NZ><<<gridM, blkM, 0, stream>>>(cur, g2, g0, base, Wm + 4096,
        nullptr, nullptr, nullptr, nullptr,
        cur, lgb + 5 * LGsz, g3, ggb + 5 * GGsz);

    prep_base_k<<<8, 256, 0, stream>>>(lgb + 5 * LGsz, nullptr, ggb + 5 * GGsz, nullptr,
                                       Wm + 5120, bm + 160, base);
    layer_main_t<NZ><<<gridM, blkM, 0, stream>>>(cur, g3, nullptr, base, Wm + 5120,
        f3s, nullptr, nullptr, nullptr,
        cur, lgb + 6 * LGsz, g2, ggb + 6 * GGsz);

    layer_out_t<NZ><<<gridF, blkF, 0, stream>>>(cur, lgb + 6 * LGsz, lgb + 2 * LGsz,
                                                g2, g1, ggb + 6 * GGsz, ggb + 2 * GGsz,
                                                W8, b8, out);
}

static size_t ws_req(int nz) {
    return LLsz * 2 * sizeof(unsigned short)
         + (size_t)4 * nz * GLsz * sizeof(float)
         + (7 * LGsz + 7 * GGsz + 2048 * 32) * sizeof(float);
}

extern "C" void kernel_launch(void* const* d_in, const int* in_sizes, int n_in,
                              void* d_out, int out_size, void* d_ws, size_t ws_size,
                              hipStream_t stream) {
    const float* channel = (const float*)d_in[0];
    const float* W1 = (const float*)d_in[1];
    const float* b1 = (const float*)d_in[2];
    const float* Wm = (const float*)d_in[3];
    const float* bm = (const float*)d_in[4];
    const float* W8 = (const float*)d_in[5];
    const float* b8 = (const float*)d_in[6];
    float* out = (float*)d_out;

    if (ws_size >= ws_req(4)) {
        run_pipeline<4>(channel, W1, b1, Wm, bm, W8, b8, out, out_size, d_ws, stream);
    } else if (ws_size >= ws_req(2)) {
        run_pipeline<2>(channel, W1, b1, Wm, bm, W8, b8, out, out_size, d_ws, stream);
    } else {
        run_pipeline<1>(channel, W1, b1, Wm, bm, W8, b8, out, out_size, d_ws, stream);
    }
}

// Round 11
// 331.809 us; speedup vs baseline: 1.3075x; 1.2147x over previous
//
#include <hip/hip_runtime.h>

// RISnetPIv2: B=128, U=16, A=1024, FEAT=4, INFO=8.
// Round-11: r10 (403us; MFMA + single-wave pair-tiled blocks) with prologue
// amortization:
//  - cgl computed by 2 MFMAs (A = bf16(g)/residual split across lane halves,
//    B = Wgl-high / Wgl-residual) -> lands directly in the C layout (cT).
//    Removes 64 pk_fma + cglT LDS staging + 2 prologue barriers. ~2^-17 err.
//  - NZ=2: 4 pair-iterations per wave (was 2) -> half the prologues for the
//    same total work; gl partial traffic halves.
// Everything else (B K-split W+Wres, per-iter LDS transpose of ch0-7, skip
// paths, plane-layout gl) carried unchanged from r10 (HW-verified pass).

#define NB 128
#define NU 16
#define NA 1024

typedef float v2f __attribute__((ext_vector_type(2)));
typedef __attribute__((ext_vector_type(8))) short bf16x8;
typedef __attribute__((ext_vector_type(16))) float f32x16;

static constexpr float PI_F = 3.14159265358979323846f;

__device__ __forceinline__ void pk_fma_acc(v2f& acc, v2f a, v2f b) {
    asm("v_pk_fma_f32 %0, %1, %2, %0" : "+v"(acc) : "v"(a), "v"(b));
}
__device__ __forceinline__ unsigned int cvtpk(float a, float b) {
    unsigned int r;
    asm("v_cvt_pk_bf16_f32 %0, %1, %2" : "=v"(r) : "v"(a), "v"(b));
    return r;  // lo = bf16(a), hi = bf16(b), RNE
}
__device__ __forceinline__ void unpack8(uint4 v, float x[8]) {
    x[0] = __uint_as_float(v.x << 16); x[1] = __uint_as_float(v.x & 0xffff0000u);
    x[2] = __uint_as_float(v.y << 16); x[3] = __uint_as_float(v.y & 0xffff0000u);
    x[4] = __uint_as_float(v.z << 16); x[5] = __uint_as_float(v.z & 0xffff0000u);
    x[6] = __uint_as_float(v.w << 16); x[7] = __uint_as_float(v.w & 0xffff0000u);
}
__device__ __forceinline__ void store8f(unsigned short* p, const float y[8]) {
    uint4 v;
    v.x = cvtpk(y[0], y[1]); v.y = cvtpk(y[2], y[3]);
    v.z = cvtpk(y[4], y[5]); v.w = cvtpk(y[6], y[7]);
    *reinterpret_cast<uint4*>(p) = v;
}
__device__ __forceinline__ float treesum16(f32x16 v) {
    float a0 = v[0] + v[1], a1 = v[2] + v[3], a2 = v[4] + v[5], a3 = v[6] + v[7];
    float a4 = v[8] + v[9], a5 = v[10] + v[11], a6 = v[12] + v[13], a7 = v[14] + v[15];
    float b0 = a0 + a1, b1 = a2 + a3, b2 = a4 + a5, b3 = a6 + a7;
    return (b0 + b1) + (b2 + b3);
}

// 3-level channel-merging butterfly (layer_first only, proven r7/r9/r10)
__device__ __forceinline__ float merge3v(const v2f* y, int lane) {
    float w[4];
    const bool s0 = (lane & 1) != 0;
#pragma unroll
    for (int k = 0; k < 4; ++k) {
        float lo = s0 ? y[k].y : y[k].x;
        float hi = s0 ? y[k].x : y[k].y;
        w[k] = lo + __shfl_xor(hi, 1, 64);
    }
    const bool s1 = (lane & 2) != 0;
#pragma unroll
    for (int k = 0; k < 2; ++k) {
        float lo = s1 ? w[2 * k + 1] : w[2 * k];
        float hi = s1 ? w[2 * k] : w[2 * k + 1];
        w[k] = lo + __shfl_xor(hi, 2, 64);
    }
    const bool s2 = (lane & 4) != 0;
    float lo = s2 ? w[1] : w[0];
    float hi = s2 ? w[0] : w[1];
    return lo + __shfl_xor(hi, 4, 64);
}

// ---------------- Layer 1 (VALU; gl -> plane layout) — unchanged from r10 ---
template <int NZ>
__global__ __launch_bounds__(128) void layer_first_t(
    const float* __restrict__ ch, const float* __restrict__ W1,
    const float* __restrict__ b1, unsigned short* __restrict__ ll_out,
    float* __restrict__ lg_out, float* __restrict__ gl_out,
    float* __restrict__ gg_out)
{
    constexpr int UN = NU / NZ;
    const int b = blockIdx.x;
    const int a = blockIdx.y * 128 + threadIdx.x;
    const int uz = blockIdx.z;
    const int lane = threadIdx.x & 63;
    const int tid = threadIdx.x;

    __shared__ float s_lg[UN][8];
    __shared__ float s_gg[8];
    for (int t = tid; t < UN * 8; t += 128) s_lg[t >> 3][t & 7] = 0.f;
    if (tid >= 64 && tid < 72) s_gg[tid & 7] = 0.f;
    __syncthreads();

    v2f glacc2[4], ggacc2[4];
#pragma unroll
    for (int i = 0; i < 4; ++i) { glacc2[i] = v2f{0.f, 0.f}; ggacc2[i] = v2f{0.f, 0.f}; }

#pragma unroll
    for (int k = 0; k < UN; ++k) {
        const int u = uz * UN + k;
        float x[4];
#pragma unroll
        for (int c = 0; c < 4; ++c)
            x[c] = ch[(((size_t)b * 4 + c) * NU + u) * NA + a];

        v2f y2[16];
        const v2f* b2 = reinterpret_cast<const v2f*>(b1);
#pragma unroll
        for (int o = 0; o < 16; ++o) y2[o] = b2[o];
#pragma unroll
        for (int c = 0; c < 4; ++c) {
            const v2f xx = v2f{x[c], x[c]};
#pragma unroll
            for (int j = 0; j < 4; ++j) {
                const v2f* wr = reinterpret_cast<const v2f*>(W1 + (j * 4 + c) * 8);
#pragma unroll
                for (int oi = 0; oi < 4; ++oi)
                    pk_fma_acc(y2[j * 4 + oi], xx, wr[oi]);
            }
        }
#pragma unroll
        for (int o = 0; o < 16; ++o)
            y2[o] = v2f{__builtin_fmaxf(y2[o].x, 0.f), __builtin_fmaxf(y2[o].y, 0.f)};

        const size_t xoff = (((size_t)(b * NU + u)) * NA + a) * 8;
        {
            uint4 v;
            v.x = cvtpk(y2[0].x, y2[0].y); v.y = cvtpk(y2[1].x, y2[1].y);
            v.z = cvtpk(y2[2].x, y2[2].y); v.w = cvtpk(y2[3].x, y2[3].y);
            *reinterpret_cast<uint4*>(ll_out + xoff) = v;
        }
#pragma unroll
        for (int i = 0; i < 4; ++i) {
            glacc2[i] += y2[8 + i];
            ggacc2[i] += y2[12 + i];
        }
        float lr = merge3v(y2 + 4, lane);
        atomicAdd(&s_lg[k][lane & 7], lr);
    }
    {   // gl partial, channel-plane layout [uz][b][c][a]
        const float invU = 1.f / 16.f;
        float ga[8];
#pragma unroll
        for (int i = 0; i < 4; ++i) { ga[2*i] = glacc2[i].x; ga[2*i+1] = glacc2[i].y; }
#pragma unroll
        for (int c = 0; c < 8; ++c)
            gl_out[(((size_t)uz * NB + b) * 8 + c) * NA + a] = ga[c] * invU;
    }
    float gga[8];
#pragma unroll
    for (int i = 0; i < 4; ++i) { gga[2*i] = ggacc2[i].x; gga[2*i+1] = ggacc2[i].y; }
    float gr = merge3v(reinterpret_cast<const v2f*>(gga), lane);
    atomicAdd(&s_gg[lane & 7], gr);
    __syncthreads();
    for (int t = tid; t < UN * 8; t += 128)
        atomicAdd(lg_out + ((size_t)b * NU + uz * UN + (t >> 3)) * 8 + (t & 7),
                  s_lg[t >> 3][t & 7]);
    if (tid >= 64 && tid < 72)
        atomicAdd(gg_out + b * 8 + (tid & 7), s_gg[tid & 7]);
}

// -------- prep: base[b,u,32] = bias + lg·W_lg + gg·W_gg (unchanged) --------
__global__ __launch_bounds__(256) void prep_base_k(
    const float* __restrict__ lg_sum, const float* __restrict__ lg_skip,
    const float* __restrict__ gg_sum, const float* __restrict__ gg_skip,
    const float* __restrict__ Wl, const float* __restrict__ bl,
    float* __restrict__ base)
{
    const int t = blockIdx.x * 256 + threadIdx.x;  // b*16+u
    if (t >= NB * NU) return;
    const int b = t >> 4;
    const float invA = 1.f / 1024.f, invUA = 1.f / 16384.f;
    float lg[8], gg[8];
#pragma unroll
    for (int c = 0; c < 8; ++c) {
        float v = lg_sum[t * 8 + c] * invA;
        if (lg_skip) v = (v + lg_skip[t * 8 + c] * invA) * 0.5f;
        lg[c] = v;
    }
#pragma unroll
    for (int c = 0; c < 8; ++c) {
        float v = gg_sum[b * 8 + c] * invUA;
        if (gg_skip) v = (v + gg_skip[b * 8 + c] * invUA) * 0.5f;
        gg[c] = v;
    }
    float y[32];
#pragma unroll
    for (int o = 0; o < 32; ++o) y[o] = bl[o];
#pragma unroll
    for (int j = 0; j < 4; ++j)
#pragma unroll
        for (int c = 0; c < 8; ++c) {
            const float* wl = Wl + (j * 32 + 8 + c) * 8;
            const float* wg = Wl + (j * 32 + 24 + c) * 8;
#pragma unroll
            for (int oi = 0; oi < 8; ++oi) {
                y[j * 8 + oi] = fmaf(lg[c], wl[oi], y[j * 8 + oi]);
                y[j * 8 + oi] = fmaf(gg[c], wg[oi], y[j * 8 + oi]);
            }
        }
#pragma unroll
    for (int o = 0; o < 32; ++o) base[t * 32 + o] = y[o];
}

// ---------------- Layers 2..7: MFMA, single-wave, pair-tiled ----------------
// Wave = 32 antennas x 2 users per iteration; cgl via 2 MFMAs (no LDS stage).
template <int NZ>
__global__ __launch_bounds__(64) void layer_main_t(
    const unsigned short* ll_in, const float* __restrict__ gl_in,
    const float* __restrict__ gl_skip, const float* __restrict__ base,
    const float* __restrict__ Wl,
    const unsigned short* __restrict__ ll_skip,          // layer 7: f3 ll
    const float* __restrict__ ch, const float* __restrict__ W1,
    const float* __restrict__ b1,                        // layer 5: recompute f1
    unsigned short* ll_out, float* __restrict__ lg_out,
    float* __restrict__ gl_out, float* __restrict__ gg_out)
{
    constexpr int UN = NU / NZ;
    const int b = blockIdx.x;
    const int lane = threadIdx.x;       // 0..63
    const int o = lane & 31;
    const int h4 = 4 * (lane >> 5);
    const int half = lane >> 5;
    const int a32 = blockIdx.y * 32 + o;
    const int uz = blockIdx.z;
    const bool lohalf = lane < 32;

    __shared__ float s_lg[UN][8];
    __shared__ float s_gg[8];
    __shared__ float myl[8 * 68];       // per-iter ch0-7 transpose buffer only
    for (int t = lane; t < UN * 8; t += 64) s_lg[t >> 3][t & 7] = 0.f;
    if (lane < 8) s_gg[lane] = 0.f;
    __syncthreads();

    const int jbr = o >> 3, oi = o & 7;

    // ---- main B fragment: col o; k0-7 = bf16(W_ll), k8-15 = residual ----
    bf16x8 Bfrag;
    {
        unsigned int t4[4];
#pragma unroll
        for (int r = 0; r < 4; ++r) {
            float w0 = Wl[(jbr * 32 + 2 * r) * 8 + oi];
            float w1 = Wl[(jbr * 32 + 2 * r + 1) * 8 + oi];
            float h0 = __uint_as_float(cvtpk(w0, w0) << 16);
            float h1 = __uint_as_float(cvtpk(w1, w1) << 16);
            t4[r] = cvtpk(lohalf ? w0 : (w0 - h0), lohalf ? w1 : (w1 - h1));
        }
        uint4 bw = make_uint4(t4[0], t4[1], t4[2], t4[3]);
        Bfrag = __builtin_bit_cast(bf16x8, bw);
    }

    // ---- gl gather (all lanes; both halves read the same antenna) ----
    float g[8];
#pragma unroll
    for (int c = 0; c < 8; ++c) {
        float s = 0.f;
#pragma unroll
        for (int z = 0; z < NZ; ++z)
            s += gl_in[(((size_t)z * NB + b) * 8 + c) * NA + a32];
        g[c] = s;
    }
    if (gl_skip) {
#pragma unroll
        for (int c = 0; c < 8; ++c) {
            float s = 0.f;
#pragma unroll
            for (int z = 0; z < NZ; ++z)
                s += gl_skip[(((size_t)z * NB + b) * 8 + c) * NA + a32];
            g[c] = (g[c] + s) * 0.5f;
        }
    }

    // ---- cT = g·W_gl via 2 MFMAs (A = gh/gres split; B = Wh, then Wres) ----
    f32x16 cT;
    {
        bf16x8 Ag, Bh, Br;
        {
            unsigned int t4[4];
#pragma unroll
            for (int r = 0; r < 4; ++r) {
                float g0 = g[2 * r], g1 = g[2 * r + 1];
                float h0 = __uint_as_float(cvtpk(g0, g0) << 16);
                float h1 = __uint_as_float(cvtpk(g1, g1) << 16);
                t4[r] = cvtpk(lohalf ? g0 : (g0 - h0), lohalf ? g1 : (g1 - h1));
            }
            uint4 u = make_uint4(t4[0], t4[1], t4[2], t4[3]);
            Ag = __builtin_bit_cast(bf16x8, u);
        }
        {
            unsigned int th[4], tr[4];
#pragma unroll
            for (int r = 0; r < 4; ++r) {
                float w0 = Wl[(jbr * 32 + 16 + 2 * r) * 8 + oi];
                float w1 = Wl[(jbr * 32 + 16 + 2 * r + 1) * 8 + oi];
                float h0 = __uint_as_float(cvtpk(w0, w0) << 16);
                float h1 = __uint_as_float(cvtpk(w1, w1) << 16);
                th[r] = cvtpk(w0, w1);
                tr[r] = cvtpk(w0 - h0, w1 - h1);
            }
            uint4 uh = make_uint4(th[0], th[1], th[2], th[3]);
            uint4 ur = make_uint4(tr[0], tr[1], tr[2], tr[3]);
            Bh = __builtin_bit_cast(bf16x8, uh);
            Br = __builtin_bit_cast(bf16x8, ur);
        }
        f32x16 z16;
#pragma unroll
        for (int r = 0; r < 16; ++r) z16[r] = 0.f;
        cT = __builtin_amdgcn_mfma_f32_32x32x16_bf16(Ag, Bh, z16, 0, 0, 0);
        cT = __builtin_amdgcn_mfma_f32_32x32x16_bf16(Ag, Br, cT, 0, 0, 0);
    }

    f32x16 acc;
#pragma unroll
    for (int r = 0; r < 16; ++r) acc[r] = 0.f;

    const unsigned short* llrow =
        ll_in + (((size_t)(b * NU + uz * UN + half)) * NA + a32) * 8;
    const size_t pstride = (size_t)2 * NA * 8;    // pair stride (2 users)
    uint4 xv = *reinterpret_cast<const uint4*>(llrow);

#pragma unroll
    for (int kp = 0; kp < UN / 2; ++kp) {
        const int u0 = uz * UN + 2 * kp;
        uint4 xnext = xv;
        if (kp + 1 < UN / 2)
            xnext = *reinterpret_cast<const uint4*>(llrow + (size_t)(kp + 1) * pstride);

        const float bse0 = base[(b * NU + u0) * 32 + o];
        const float bse1 = base[(b * NU + u0 + 1) * 32 + o];

        uint4 xs;
        xs.x = (unsigned)__shfl_xor((int)xv.x, 32, 64);
        xs.y = (unsigned)__shfl_xor((int)xv.y, 32, 64);
        xs.z = (unsigned)__shfl_xor((int)xv.z, 32, 64);
        xs.w = (unsigned)__shfl_xor((int)xv.w, 32, 64);
        uint4 a0u, a1u;
        a0u.x = lohalf ? xv.x : xs.x; a0u.y = lohalf ? xv.y : xs.y;
        a0u.z = lohalf ? xv.z : xs.z; a0u.w = lohalf ? xv.w : xs.w;
        a1u.x = lohalf ? xs.x : xv.x; a1u.y = lohalf ? xs.y : xv.y;
        a1u.z = lohalf ? xs.z : xv.z; a1u.w = lohalf ? xs.w : xv.w;
        bf16x8 A0 = __builtin_bit_cast(bf16x8, a0u);
        bf16x8 A1 = __builtin_bit_cast(bf16x8, a1u);

        f32x16 d0 = __builtin_amdgcn_mfma_f32_32x32x16_bf16(A0, Bfrag, cT, 0, 0, 0);
        f32x16 d1 = __builtin_amdgcn_mfma_f32_32x32x16_bf16(A1, Bfrag, cT, 0, 0, 0);
#pragma unroll
        for (int r = 0; r < 16; ++r) {
            d0[r] = __builtin_fmaxf(d0[r] + bse0, 0.f);
            d1[r] = __builtin_fmaxf(d1[r] + bse1, 0.f);
        }

        // lg (channels 8..15): per-u rowsum over the 32 antennas
        float red0 = treesum16(d0);
        red0 += __shfl_xor(red0, 32, 64);
        if (lane >= 8 && lane < 16) atomicAdd(&s_lg[2 * kp][lane - 8], red0);
        float red1 = treesum16(d1);
        red1 += __shfl_xor(red1, 32, 64);
        if (lane >= 8 && lane < 16) atomicAdd(&s_lg[2 * kp + 1][lane - 8], red1);

        // gl/gg accumulate (both users into one acc)
#pragma unroll
        for (int r = 0; r < 16; ++r) acc[r] += d0[r] + d1[r];

        // transpose ch0-7 of both users: myl[c][ant + 32*half]
        if (o < 8) {
#pragma unroll
            for (int q = 0; q < 4; ++q) {
                *reinterpret_cast<float4*>(&myl[o * 68 + q * 8 + h4]) =
                    make_float4(d0[4*q], d0[4*q+1], d0[4*q+2], d0[4*q+3]);
                *reinterpret_cast<float4*>(&myl[o * 68 + 32 + q * 8 + h4]) =
                    make_float4(d1[4*q], d1[4*q+1], d1[4*q+2], d1[4*q+3]);
            }
        }
        __syncthreads();
        float y[8];
#pragma unroll
        for (int c = 0; c < 8; ++c) y[c] = myl[c * 68 + lane];

        // skip paths (antenna-major; per-lane user u0+half)
        const int u_lane = u0 + half;
        const size_t xoff = (((size_t)(b * NU + u_lane)) * NA + a32) * 8;
        if (ll_skip) {
            float s[8];
            unpack8(*reinterpret_cast<const uint4*>(ll_skip + xoff), s);
#pragma unroll
            for (int c = 0; c < 8; ++c) y[c] = (y[c] + s[c]) * 0.5f;
        } else if (ch) {
            float xc[4];
#pragma unroll
            for (int c = 0; c < 4; ++c)
                xc[c] = ch[(((size_t)b * 4 + c) * NU + u_lane) * NA + a32];
            float s[8];
#pragma unroll
            for (int i = 0; i < 8; ++i) s[i] = b1[i];
#pragma unroll
            for (int c = 0; c < 4; ++c)
#pragma unroll
                for (int i = 0; i < 8; ++i)
                    s[i] = fmaf(xc[c], W1[c * 8 + i], s[i]);
#pragma unroll
            for (int i = 0; i < 8; ++i)
                y[i] = (y[i] + __builtin_fmaxf(s[i], 0.f)) * 0.5f;
        }
        store8f(ll_out + xoff, y);
        __syncthreads();    // myl reads done before next pair's writes
        xv = xnext;
    }

    // gg: total rowsum (consumer divides by 16384)
    float gr = treesum16(acc);
    gr += __shfl_xor(gr, 32, 64);
    if (lane >= 24 && lane < 32) atomicAdd(&s_gg[lane - 24], gr);

    // gl store (channels 16..23), plane layout, scaled 1/U
    if (o >= 16 && o < 24) {
        const float invU = 1.f / 16.f;
        float* gp = gl_out + (((size_t)uz * NB + b) * 8 + (o - 16)) * NA
                  + blockIdx.y * 32;
#pragma unroll
        for (int q = 0; q < 4; ++q)
            *reinterpret_cast<float4*>(gp + q * 8 + h4) =
                make_float4(acc[4*q]*invU, acc[4*q+1]*invU, acc[4*q+2]*invU, acc[4*q+3]*invU);
    }
    __syncthreads();
    for (int t = lane; t < UN * 8; t += 64)
        atomicAdd(lg_out + ((size_t)b * NU + uz * UN + (t >> 3)) * 8 + (t & 7),
                  s_lg[t >> 3][t & 7]);
    if (lane < 8)
        atomicAdd(gg_out + b * 8 + lane, s_gg[lane]);
}

// ---------------- Layer 8 (gl plane layout) — unchanged from r10 ----------------
template <int NZ>
__global__ __launch_bounds__(128) void layer_out_t(
    const unsigned short* __restrict__ ll,
    const float* __restrict__ lg7, const float* __restrict__ lg3,
    const float* __restrict__ gl7, const float* __restrict__ gl3,
    const float* __restrict__ gg7, const float* __restrict__ gg3,
    const float* __restrict__ W8, const float* __restrict__ b8,
    float* __restrict__ out)
{
    constexpr int UN = NU / NZ;
    const int b = blockIdx.x;
    const int a = blockIdx.y * 128 + threadIdx.x;
    const int uz = blockIdx.z;
    const float invA = 1.f / 1024.f, invUA = 1.f / 16384.f, invU = 1.f / 16.f;

    float acc = 0.f;
#pragma unroll
    for (int k = 0; k < UN; ++k) {
        const int u = uz * UN + k;
        float x[8];
        unpack8(*reinterpret_cast<const uint4*>(
            ll + (((size_t)(b * NU + u)) * NA + a) * 8), x);
#pragma unroll
        for (int c = 0; c < 8; ++c) acc += x[c] * W8[c];
    }
    acc *= invU;

    if (uz == 0) {
        float sb = b8[0];
#pragma unroll
        for (int c = 0; c < 8; ++c) {
            float s7 = 0.f, s3 = 0.f;
#pragma unroll
            for (int u = 0; u < NU; ++u) {
                s7 += lg7[(b * NU + u) * 8 + c];
                s3 += lg3[(b * NU + u) * 8 + c];
            }
            sb += ((s7 * invA + s3 * invA) * 0.5f * invU) * W8[8 + c];
        }
#pragma unroll
        for (int c = 0; c < 8; ++c)
            sb += ((gg7[b * 8 + c] + gg3[b * 8 + c]) * invUA * 0.5f) * W8[24 + c];

        float s7[8], s3[8];
#pragma unroll
        for (int i = 0; i < 8; ++i) { s7[i] = 0.f; s3[i] = 0.f; }
#pragma unroll
        for (int z = 0; z < NZ; ++z)
#pragma unroll
            for (int i = 0; i < 8; ++i) {
                s7[i] += gl7[(((size_t)z * NB + b) * 8 + i) * NA + a];
                s3[i] += gl3[(((size_t)z * NB + b) * 8 + i) * NA + a];
            }
#pragma unroll
        for (int i = 0; i < 8; ++i)
            acc += 0.5f * (s7[i] + s3[i]) * W8[16 + i];
        acc += sb;
    }
    atomicAdd(out + (size_t)b * NA + a, acc * PI_F);
}

// ---------------- host ----------------
static constexpr size_t LLsz = (size_t)NB * NU * NA * 8;
static constexpr size_t GLsz = (size_t)NB * NA * 8;
static constexpr size_t LGsz = (size_t)NB * NU * 8;
static constexpr size_t GGsz = (size_t)NB * 8;

template <int NZ>
static void run_pipeline(const float* channel, const float* W1, const float* b1,
                         const float* Wm, const float* bm, const float* W8,
                         const float* b8, float* out, int out_bytes,
                         void* d_ws, hipStream_t stream)
{
    unsigned short* cur = (unsigned short*)d_ws;
    unsigned short* f3s = cur + LLsz;
    float* glb = (float*)(f3s + LLsz);
    float* g0 = glb;
    float* g1 = glb + (size_t)NZ * GLsz;
    float* g2 = glb + (size_t)2 * NZ * GLsz;
    float* g3 = glb + (size_t)3 * NZ * GLsz;
    float* lgb = glb + (size_t)4 * NZ * GLsz;
    float* ggb = lgb + 7 * LGsz;
    float* base = ggb + 7 * GGsz;

    hipMemsetAsync(lgb, 0, (7 * LGsz + 7 * GGsz) * sizeof(float), stream);
    hipMemsetAsync(out, 0, out_bytes, stream);

    dim3 gridF(NB, NA / 128, NZ), blkF(128);
    dim3 gridM(NB, NA / 32, NZ), blkM(64);

    layer_first_t<NZ><<<gridF, blkF, 0, stream>>>(channel, W1, b1, cur, lgb, g0, ggb);

    prep_base_k<<<8, 256, 0, stream>>>(lgb, nullptr, ggb, nullptr, Wm, bm, base);
    layer_main_t<NZ><<<gridM, blkM, 0, stream>>>(cur, g0, nullptr, base, Wm,
        nullptr, nullptr, nullptr, nullptr,
        cur, lgb + 1 * LGsz, g2, ggb + 1 * GGsz);

    prep_base_k<<<8, 256, 0, stream>>>(lgb + 1 * LGsz, nullptr, ggb + 1 * GGsz, nullptr,
                                       Wm + 1024, bm + 32, base);
    layer_main_t<NZ><<<gridM, blkM, 0, stream>>>(cur, g2, nullptr, base, Wm + 1024,
        nullptr, nullptr, nullptr, nullptr,
        f3s, lgb + 2 * LGsz, g1, ggb + 2 * GGsz);

    prep_base_k<<<8, 256, 0, stream>>>(lgb + 2 * LGsz, nullptr, ggb + 2 * GGsz, nullptr,
                                       Wm + 2048, bm + 64, base);
    layer_main_t<NZ><<<gridM, blkM, 0, stream>>>(f3s, g1, nullptr, base, Wm + 2048,
        nullptr, nullptr, nullptr, nullptr,
        cur, lgb + 3 * LGsz, g3, ggb + 3 * GGsz);

    prep_base_k<<<8, 256, 0, stream>>>(lgb + 3 * LGsz, nullptr, ggb + 3 * GGsz, nullptr,
                                       Wm + 3072, bm + 96, base);
    layer_main_t<NZ><<<gridM, blkM, 0, stream>>>(cur, g3, nullptr, base, Wm + 3072,
        nullptr, channel, W1, b1,
        cur, lgb + 4 * LGsz, g2, ggb + 4 * GGsz);

    prep_base_k<<<8, 256, 0, stream>>>(lgb + 4 * LGsz, lgb, ggb + 4 * GGsz, ggb,
                                       Wm + 4096, bm + 128, base);
    layer_main_t<NZ><<<gridM, blkM, 0, stream>>>(cur, g2, g0, base, Wm + 4096,
        nullptr, nullptr, nullptr, nullptr,
        cur, lgb + 5 * LGsz, g3, ggb + 5 * GGsz);

    prep_base_k<<<8, 256, 0, stream>>>(lgb + 5 * LGsz, nullptr, ggb + 5 * GGsz, nullptr,
                                       Wm + 5120, bm + 160, base);
    layer_main_t<NZ><<<gridM, blkM, 0, stream>>>(cur, g3, nullptr, base, Wm + 5120,
        f3s, nullptr, nullptr, nullptr,
        cur, lgb + 6 * LGsz, g2, ggb + 6 * GGsz);

    layer_out_t<NZ><<<gridF, blkF, 0, stream>>>(cur, lgb + 6 * LGsz, lgb + 2 * LGsz,
                                                g2, g1, ggb + 6 * GGsz, ggb + 2 * GGsz,
                                                W8, b8, out);
}

static size_t ws_req(int nz) {
    return LLsz * 2 * sizeof(unsigned short)
         + (size_t)4 * nz * GLsz * sizeof(float)
         + (7 * LGsz + 7 * GGsz + 2048 * 32) * sizeof(float);
}

extern "C" void kernel_launch(void* const* d_in, const int* in_sizes, int n_in,
                              void* d_out, int out_size, void* d_ws, size_t ws_size,
                              hipStream_t stream) {
    const float* channel = (const float*)d_in[0];
    const float* W1 = (const float*)d_in[1];
    const float* b1 = (const float*)d_in[2];
    const float* Wm = (const float*)d_in[3];
    const float* bm = (const float*)d_in[4];
    const float* W8 = (const float*)d_in[5];
    const float* b8 = (const float*)d_in[6];
    float* out = (float*)d_out;

    if (ws_size >= ws_req(2)) {
        run_pipeline<2>(channel, W1, b1, Wm, bm, W8, b8, out, out_size, d_ws, stream);
    } else {
        run_pipeline<1>(channel, W1, b1, Wm, bm, W8, b8, out, out_size, d_ws, stream);
    }
}